// Round 5
// baseline (291.523 us; speedup 1.0000x reference)
//
#include <hip/hip_runtime.h>
#include <math.h>

namespace {

constexpr int B_ = 256;
constexpr int R_ = 1152;
constexpr int C_ = 10;
constexpr int O_ = 16;
constexpr int I_ = 8;
constexpr int CO_ = C_ * O_;          // 160
constexpr int WRI_ = C_ * O_ * I_;    // 1280 floats of W per route

// ---- fast path params ----
constexpr int KS2_ = 64;              // r-splits in k_s3
constexpr int RC2_ = R_ / KS2_;       // 18 routes per block
constexpr int RT_  = 4;               // routes per k_a4 block

// ---- fallback path params ----
constexpr int KSF_ = 16;
constexpr int RCF_ = R_ / KSF_;       // 72
constexpr int MBF_ = 16;

__device__ __forceinline__ float squashf(float s) {
    // faithful to reference: s^2*s/((1+s^2)*sqrt(s^2)) == s*|s|/(1+s^2)
    return s * fabsf(s) / (1.0f + s * s);
}

// ===========================================================================
// FAST PATH
// ===========================================================================

// x[b,r,i] -> xT[r,b,i].  tile: 8 b x 32 r.  grid 36*32=1152, 256 thr.
__global__ __launch_bounds__(256) void k_tr(const float* __restrict__ x,
                                            float* __restrict__ xT) {
    __shared__ float t[8][32][8];
    const int r0 = (blockIdx.x % 36) * 32;
    const int b0 = (blockIdx.x / 36) * 8;
    const int tid = threadIdx.x;
    {
        const int rl = tid & 31, bl = tid >> 5;
        const float4* p = (const float4*)(x + ((size_t)(b0 + bl) * R_ + (r0 + rl)) * I_);
        const float4 a0 = p[0], a1 = p[1];
        float* d = &t[bl][rl][0];
        *(float4*)d = a0;
        *(float4*)(d + 4) = a1;
    }
    __syncthreads();
    {
        const int f = tid & 7, rw = tid >> 3;   // f = b-local
        const float* s8 = &t[f][rw][0];
        const float4 a0 = *(const float4*)s8, a1 = *(const float4*)(s8 + 4);
        float* d = xT + ((size_t)(r0 + rw) * B_ + (b0 + f)) * I_;
        *(float4*)d = a0;
        *(float4*)(d + 4) = a1;
    }
}

// spart[ks,co,b] = sum_{r in chunk} softmax_r(bijT[c,:]) * dot(W[r,c,o,:], xT[r,b,:])
// grid (C_, KS2_), 256 thr = b.  Softmax over routes computed in-block from
// bijT (block-wide reduce), eliminating the separate k_soft kernel.
// W / bij wave-uniform -> scalar loads.  Atomic-free: partials per ks slice.
template <bool UNIFORM>
__global__ __launch_bounds__(256) void k_s3(const float* __restrict__ xT,
                                            const float* __restrict__ Wm,
                                            const float* __restrict__ bijT,
                                            float* __restrict__ spart) {
    const int b  = threadIdx.x;
    const int c  = blockIdx.x;          // 0..9
    const int ks = blockIdx.y;          // 0..KS2_-1
    const int r0 = ks * RC2_;

    __shared__ float sred[8];

    float bm = 0.f, inv = 1.0f / (float)R_;
    if (!UNIFORM) {
        const float* bc = bijT + (size_t)c * R_;
        float m = -1e30f;
        #pragma unroll
        for (int k = 0; k < 5; ++k) {
            const int r = b + 256 * k;
            if (r < R_) m = fmaxf(m, bc[r]);
        }
        #pragma unroll
        for (int off = 32; off > 0; off >>= 1)
            m = fmaxf(m, __shfl_down(m, off, 64));
        if ((b & 63) == 0) sred[b >> 6] = m;
        __syncthreads();
        bm = fmaxf(fmaxf(sred[0], sred[1]), fmaxf(sred[2], sred[3]));

        float se = 0.f;
        #pragma unroll
        for (int k = 0; k < 5; ++k) {
            const int r = b + 256 * k;
            if (r < R_) se += expf(bc[r] - bm);
        }
        #pragma unroll
        for (int off = 32; off > 0; off >>= 1)
            se += __shfl_down(se, off, 64);
        if ((b & 63) == 0) sred[4 + (b >> 6)] = se;
        __syncthreads();
        inv = 1.0f / (sred[4] + sred[5] + sred[6] + sred[7]);
    }

    float acc[O_];
    #pragma unroll
    for (int o = 0; o < O_; ++o) acc[o] = 0.f;

    const float4* xp4 = (const float4*)(xT + ((size_t)r0 * B_ + b) * I_);
    const float*  wp  = Wm + ((size_t)r0 * C_ + c) * O_ * I_;
    const float*  bcr = bijT + (size_t)c * R_ + r0;

    float4 x0 = xp4[0], x1 = xp4[1];
    float  bw = UNIFORM ? 0.f : bcr[0];

    #pragma unroll 1
    for (int r = 0; r < RC2_; ++r) {
        const float4 cx0 = x0, cx1 = x1;
        const float  cbw = bw;
        if (r + 1 < RC2_) {                       // prefetch next r
            xp4 += (B_ * I_) / 4;
            x0 = xp4[0];
            x1 = xp4[1];
            if (!UNIFORM) bw = bcr[r + 1];
        }
        const float cw = UNIFORM ? (1.0f / (float)R_) : expf(cbw - bm) * inv;
        #pragma unroll
        for (int o = 0; o < O_; ++o) {
            const float4 w0 = *(const float4*)(wp + o * 8);
            const float4 w1 = *(const float4*)(wp + o * 8 + 4);
            const float p0 = fmaf(cx0.y, w0.y, cx0.x * w0.x);
            const float p1 = fmaf(cx0.w, w0.w, cx0.z * w0.z);
            const float p2 = fmaf(cx1.y, w1.y, cx1.x * w1.x);
            const float p3 = fmaf(cx1.w, w1.w, cx1.z * w1.z);
            acc[o] = fmaf(cw, (p0 + p1) + (p2 + p3), acc[o]);
        }
        wp += WRI_;
    }

    float* sp = spart + ((size_t)ks * CO_ + c * O_) * B_ + b;
    #pragma unroll
    for (int o = 0; o < O_; ++o) sp[(size_t)o * B_] = acc[o];
}

// vout[b,co] = squash(sum_ks spart[ks,co,b]).  grid CO_, 256 thr.
__global__ __launch_bounds__(256) void k_v2(const float* __restrict__ spart,
                                            float* __restrict__ vout) {
    const int b  = threadIdx.x;
    const int co = blockIdx.x;
    const float* p = spart + (size_t)co * B_ + b;
    float s0 = 0.f, s1 = 0.f, s2 = 0.f, s3 = 0.f;
    #pragma unroll
    for (int k = 0; k < KS2_; k += 4) {
        s0 += p[(size_t)(k + 0) * CO_ * B_];
        s1 += p[(size_t)(k + 1) * CO_ * B_];
        s2 += p[(size_t)(k + 2) * CO_ * B_];
        s3 += p[(size_t)(k + 3) * CO_ * B_];
    }
    vout[(size_t)b * CO_ + co] = squashf((s0 + s1) + (s2 + s3));
}

// bijT[c, r0+rr] += (1/B) sum_o sum_i W[r,c,o,i] * (sum_b v[b,c,o]*xT[r,b,i])
// grid R_/RT_ blocks, 640 thr = 160 co x 4 b-groups of 64.  RT_ routes/block:
// v traffic /RT_, 4x fma per v load.  bij update folded in (one writer per
// (c,r) -> race-free).
__global__ __launch_bounds__(640) void k_a4(const float* __restrict__ xT,
                                            const float* __restrict__ Wm,
                                            const float* __restrict__ v,
                                            float* __restrict__ bijT) {
    __shared__ __align__(16) float xrow[RT_ * B_ * I_];   // 32 KB
    __shared__ float part[RT_][640];                      // 10 KB

    const int tid = threadIdx.x;
    const int r0  = blockIdx.x * RT_;

    for (int k = tid; k < RT_ * B_ * I_ / 4; k += 640)
        ((float4*)xrow)[k] = ((const float4*)(xT + (size_t)r0 * B_ * I_))[k];
    __syncthreads();

    const int co = tid % CO_;
    const int bg = tid / CO_;           // 0..3
    const int b0 = bg * 64;

    float acc[RT_][8];
    #pragma unroll
    for (int rr = 0; rr < RT_; ++rr)
        #pragma unroll
        for (int i = 0; i < 8; ++i) acc[rr][i] = 0.f;

    const float* vp = v + co;
    #pragma unroll 2
    for (int bb = 0; bb < 64; ++bb) {
        const int b = b0 + bb;
        const float vt = vp[(size_t)b * CO_];
        #pragma unroll
        for (int rr = 0; rr < RT_; ++rr) {
            const float4 y0 = *(const float4*)(&xrow[(rr * B_ + b) * I_]);
            const float4 y1 = *(const float4*)(&xrow[(rr * B_ + b) * I_ + 4]);
            acc[rr][0] = fmaf(vt, y0.x, acc[rr][0]);
            acc[rr][1] = fmaf(vt, y0.y, acc[rr][1]);
            acc[rr][2] = fmaf(vt, y0.z, acc[rr][2]);
            acc[rr][3] = fmaf(vt, y0.w, acc[rr][3]);
            acc[rr][4] = fmaf(vt, y1.x, acc[rr][4]);
            acc[rr][5] = fmaf(vt, y1.y, acc[rr][5]);
            acc[rr][6] = fmaf(vt, y1.z, acc[rr][6]);
            acc[rr][7] = fmaf(vt, y1.w, acc[rr][7]);
        }
    }

    #pragma unroll
    for (int rr = 0; rr < RT_; ++rr) {
        const float* wp = Wm + (((size_t)(r0 + rr)) * CO_ + co) * I_;
        const float4 w0 = *(const float4*)wp;
        const float4 w1 = *(const float4*)(wp + 4);
        const float p0 = fmaf(acc[rr][1], w0.y, acc[rr][0] * w0.x);
        const float p1 = fmaf(acc[rr][3], w0.w, acc[rr][2] * w0.z);
        const float p2 = fmaf(acc[rr][5], w1.y, acc[rr][4] * w1.x);
        const float p3 = fmaf(acc[rr][7], w1.w, acc[rr][6] * w1.z);
        part[rr][tid] = (p0 + p1) + (p2 + p3);
    }
    __syncthreads();

    if (tid < CO_) {
        #pragma unroll
        for (int rr = 0; rr < RT_; ++rr) {
            float a = part[rr][tid] + part[rr][CO_ + tid] +
                      part[rr][2 * CO_ + tid] + part[rr][3 * CO_ + tid];
            #pragma unroll
            for (int off = 8; off > 0; off >>= 1)
                a += __shfl_down(a, off, 16);
            if ((tid & 15) == 0)
                bijT[(size_t)(tid >> 4) * R_ + (r0 + rr)] += a * (1.0f / (float)B_);
        }
    }
}

// ===========================================================================
// FALLBACK PATH (used only if ws is too small for xT)
// ===========================================================================

template <bool UNIFORM>
__global__ __launch_bounds__(256) void k_s_f(const float* __restrict__ x,
                                             const float* __restrict__ Wm,
                                             const float* __restrict__ cij,
                                             float* __restrict__ s_out) {
    const int o  = threadIdx.x & 15;
    const int tb = threadIdx.x >> 4;
    const int b  = blockIdx.z * MBF_ + tb;
    const int c  = blockIdx.y;
    const int r0 = blockIdx.x * RCF_;

    const float* xp = x + ((size_t)b * R_ + r0) * I_;
    const float* wp = Wm + (((size_t)r0 * C_ + c) * O_ + o) * I_;
    const float* cp = cij + (size_t)r0 * C_ + c;

    float acc = 0.f;
    #pragma unroll 4
    for (int r = 0; r < RCF_; ++r) {
        const float4 xv0 = *(const float4*)(xp);
        const float4 xv1 = *(const float4*)(xp + 4);
        const float4 wv0 = *(const float4*)(wp);
        const float4 wv1 = *(const float4*)(wp + 4);
        const float p0 = fmaf(xv0.y, wv0.y, xv0.x * wv0.x);
        const float p1 = fmaf(xv0.w, wv0.w, xv0.z * wv0.z);
        const float p2 = fmaf(xv1.y, wv1.y, xv1.x * wv1.x);
        const float p3 = fmaf(xv1.w, wv1.w, xv1.z * wv1.z);
        const float cw = UNIFORM ? (1.0f / (float)R_) : cp[0];
        acc = fmaf(cw, (p0 + p1) + (p2 + p3), acc);
        xp += I_;
        wp += WRI_;
        cp += C_;
    }
    atomicAdd(&s_out[((size_t)b * C_ + c) * O_ + o], acc);
}

__global__ __launch_bounds__(256) void k_a_f(const float* __restrict__ x,
                                             const float* __restrict__ Wm,
                                             const float* __restrict__ s_in,
                                             float* __restrict__ amean) {
    __shared__ __align__(16) float wlds[2 * WRI_];
    __shared__ float red[4][2 * C_];

    const int tid = threadIdx.x;
    const int r0  = blockIdx.x * 2;

    const float* wsrc = Wm + (size_t)r0 * WRI_;
    #pragma unroll
    for (int k = 0; k < 2 * WRI_ / 256; ++k)
        wlds[tid + 256 * k] = wsrc[tid + 256 * k];
    __syncthreads();

    const int b    = tid;
    const int lane = tid & 63;
    const int wv   = tid >> 6;

    float xv[2][I_];
    const float4* xp4 = (const float4*)(x + ((size_t)b * R_ + r0) * I_);
    #pragma unroll
    for (int rr = 0; rr < 2; ++rr) {
        const float4 a0 = xp4[rr * 2 + 0];
        const float4 a1 = xp4[rr * 2 + 1];
        xv[rr][0] = a0.x; xv[rr][1] = a0.y; xv[rr][2] = a0.z; xv[rr][3] = a0.w;
        xv[rr][4] = a1.x; xv[rr][5] = a1.y; xv[rr][6] = a1.z; xv[rr][7] = a1.w;
    }

    #pragma unroll 1
    for (int c = 0; c < C_; ++c) {
        const float4* sp4 = (const float4*)(s_in + ((size_t)b * C_ + c) * O_);
        float v[O_];
        #pragma unroll
        for (int q = 0; q < 4; ++q) {
            const float4 sv = sp4[q];
            v[q * 4 + 0] = squashf(sv.x);
            v[q * 4 + 1] = squashf(sv.y);
            v[q * 4 + 2] = squashf(sv.z);
            v[q * 4 + 3] = squashf(sv.w);
        }
        #pragma unroll 1
        for (int rr = 0; rr < 2; ++rr) {
            const float4* wl4 = (const float4*)&wlds[(rr * C_ + c) * O_ * I_];
            float a = 0.f;
            #pragma unroll
            for (int o = 0; o < O_; ++o) {
                const float4 w0 = wl4[o * 2 + 0];
                const float4 w1 = wl4[o * 2 + 1];
                float u = xv[rr][0] * w0.x;
                u = fmaf(xv[rr][1], w0.y, u);
                u = fmaf(xv[rr][2], w0.z, u);
                u = fmaf(xv[rr][3], w0.w, u);
                u = fmaf(xv[rr][4], w1.x, u);
                u = fmaf(xv[rr][5], w1.y, u);
                u = fmaf(xv[rr][6], w1.z, u);
                u = fmaf(xv[rr][7], w1.w, u);
                a = fmaf(u, v[o], a);
            }
            #pragma unroll
            for (int off = 32; off > 0; off >>= 1)
                a += __shfl_down(a, off, 64);
            if (lane == 0) red[wv][rr * C_ + c] = a;
        }
    }

    __syncthreads();
    if (tid < 2 * C_) {
        const float t = red[0][tid] + red[1][tid] + red[2][tid] + red[3][tid];
        const int rr = tid / C_;
        const int c  = tid % C_;
        amean[(size_t)(r0 + rr) * C_ + c] = t * (1.0f / (float)B_);
    }
}

__global__ __launch_bounds__(256) void k_soft(const float* __restrict__ amean,
                                              float* __restrict__ bij,
                                              float* __restrict__ cij) {
    const int c   = blockIdx.x;
    const int tid = threadIdx.x;
    __shared__ float sred[4];

    float vals[5];
    float m = -1e30f;
    #pragma unroll
    for (int k = 0; k < 5; ++k) {
        const int r = tid + 256 * k;
        if (r < R_) {
            const size_t idx = (size_t)r * C_ + c;
            const float vv = bij[idx] + amean[idx];
            bij[idx] = vv;
            vals[k] = vv;
            m = fmaxf(m, vv);
        } else {
            vals[k] = -1e30f;
        }
    }
    #pragma unroll
    for (int off = 32; off > 0; off >>= 1)
        m = fmaxf(m, __shfl_down(m, off, 64));
    if ((tid & 63) == 0) sred[tid >> 6] = m;
    __syncthreads();
    const float bm = fmaxf(fmaxf(sred[0], sred[1]), fmaxf(sred[2], sred[3]));
    __syncthreads();

    float se = 0.f;
    #pragma unroll
    for (int k = 0; k < 5; ++k)
        se += (vals[k] > -1e29f) ? expf(vals[k] - bm) : 0.f;
    #pragma unroll
    for (int off = 32; off > 0; off >>= 1)
        se += __shfl_down(se, off, 64);
    if ((tid & 63) == 0) sred[tid >> 6] = se;
    __syncthreads();
    const float inv = 1.0f / (sred[0] + sred[1] + sred[2] + sred[3]);

    #pragma unroll
    for (int k = 0; k < 5; ++k) {
        const int r = tid + 256 * k;
        if (r < R_) cij[(size_t)r * C_ + c] = expf(vals[k] - bm) * inv;
    }
}

__global__ __launch_bounds__(256) void k_squash(float* __restrict__ s) {
    const int idx = blockIdx.x * 256 + threadIdx.x;
    if (idx < B_ * CO_) s[idx] = squashf(s[idx]);
}

} // namespace

extern "C" void kernel_launch(void* const* d_in, const int* in_sizes, int n_in,
                              void* d_out, int out_size, void* d_ws, size_t ws_size,
                              hipStream_t stream) {
    const float* x  = (const float*)d_in[0];   // [256,1152,8]
    const float* Wm = (const float*)d_in[1];   // [1152,10,16,8]
    float* out = (float*)d_out;                // [256,10,16] flat = 40960
    float* ws  = (float*)d_ws;

    const size_t XT_N    = (size_t)R_ * B_ * I_;        // 2,359,296 floats
    const size_t SPART_N = (size_t)KS2_ * CO_ * B_;     // 2,621,440 floats
    const size_t need_floats =
        XT_N + SPART_N + (size_t)(B_ * CO_) + (size_t)(C_ * R_);

    if (ws_size >= need_floats * sizeof(float)) {
        // ---------------- fast path ----------------
        float* xT    = ws;
        float* spart = xT + XT_N;                 // [KS2_][CO_][B_]
        float* v     = spart + SPART_N;           // [B_][CO_]
        float* bijT  = v + (size_t)B_ * CO_;      // [C_][R_]

        k_tr<<<1152, 256, 0, stream>>>(x, xT);
        hipMemsetAsync(bijT, 0, C_ * R_ * sizeof(float), stream);

        const dim3 gs(C_, KS2_);                  // 640 blocks

        // iter 0 (uniform weights; softmax(0) == 1/R)
        k_s3<true><<<gs, 256, 0, stream>>>(xT, Wm, bijT, spart);
        k_v2<<<CO_, B_, 0, stream>>>(spart, v);
        k_a4<<<R_ / RT_, 640, 0, stream>>>(xT, Wm, v, bijT);

        // iter 1 (softmax of bij computed inside k_s3)
        k_s3<false><<<gs, 256, 0, stream>>>(xT, Wm, bijT, spart);
        k_v2<<<CO_, B_, 0, stream>>>(spart, v);
        k_a4<<<R_ / RT_, 640, 0, stream>>>(xT, Wm, v, bijT);

        // iter 2: final v straight into d_out
        k_s3<false><<<gs, 256, 0, stream>>>(xT, Wm, bijT, spart);
        k_v2<<<CO_, B_, 0, stream>>>(spart, out);
    } else {
        // ---------------- fallback ----------------
        float* s_buf = ws;
        float* cij   = ws + 40960;
        float* bij   = cij + R_ * C_;
        float* amean = bij + R_ * C_;

        const dim3 gs(KSF_, C_, B_ / MBF_);

        hipMemsetAsync(bij, 0, R_ * C_ * sizeof(float), stream);

        hipMemsetAsync(s_buf, 0, B_ * CO_ * sizeof(float), stream);
        k_s_f<true><<<gs, 256, 0, stream>>>(x, Wm, cij, s_buf);
        k_a_f<<<R_ / 2, 256, 0, stream>>>(x, Wm, s_buf, amean);
        k_soft<<<C_, 256, 0, stream>>>(amean, bij, cij);

        hipMemsetAsync(s_buf, 0, B_ * CO_ * sizeof(float), stream);
        k_s_f<false><<<gs, 256, 0, stream>>>(x, Wm, cij, s_buf);
        k_a_f<<<R_ / 2, 256, 0, stream>>>(x, Wm, s_buf, amean);
        k_soft<<<C_, 256, 0, stream>>>(amean, bij, cij);

        hipMemsetAsync(out, 0, B_ * CO_ * sizeof(float), stream);
        k_s_f<false><<<gs, 256, 0, stream>>>(x, Wm, cij, out);
        k_squash<<<(B_ * CO_ + 255) / 256, 256, 0, stream>>>(out);
    }
}

// Round 6
// 222.105 us; speedup vs baseline: 1.3125x; 1.3125x over previous
//
#include <hip/hip_runtime.h>
#include <math.h>

namespace {

constexpr int B_ = 256;
constexpr int R_ = 1152;
constexpr int C_ = 10;
constexpr int O_ = 16;
constexpr int I_ = 8;
constexpr int CO_ = C_ * O_;          // 160
constexpr int WRI_ = C_ * O_ * I_;    // 1280 floats of W per route

// ---- fast path params ----
constexpr int KS2_ = 64;              // r-splits in k_s4
constexpr int RC2_ = R_ / KS2_;       // 18 routes per block
constexpr int RT_  = 4;               // routes per k_a4 block

// ---- fallback path params ----
constexpr int KSF_ = 16;
constexpr int RCF_ = R_ / KSF_;       // 72
constexpr int MBF_ = 16;

__device__ __forceinline__ float squashf(float s) {
    // faithful to reference: s^2*s/((1+s^2)*sqrt(s^2)) == s*|s|/(1+s^2)
    return s * fabsf(s) / (1.0f + s * s);
}

// ===========================================================================
// FAST PATH
// ===========================================================================

// x[b,r,i] -> xT[r,b,i].  tile: 8 b x 32 r.  grid 36*32=1152, 256 thr.
__global__ __launch_bounds__(256) void k_tr(const float* __restrict__ x,
                                            float* __restrict__ xT) {
    __shared__ float t[8][32][8];
    const int r0 = (blockIdx.x % 36) * 32;
    const int b0 = (blockIdx.x / 36) * 8;
    const int tid = threadIdx.x;
    {
        const int rl = tid & 31, bl = tid >> 5;
        const float4* p = (const float4*)(x + ((size_t)(b0 + bl) * R_ + (r0 + rl)) * I_);
        const float4 a0 = p[0], a1 = p[1];
        float* d = &t[bl][rl][0];
        *(float4*)d = a0;
        *(float4*)(d + 4) = a1;
    }
    __syncthreads();
    {
        const int f = tid & 7, rw = tid >> 3;   // f = b-local
        const float* s8 = &t[f][rw][0];
        const float4 a0 = *(const float4*)s8, a1 = *(const float4*)(s8 + 4);
        float* d = xT + ((size_t)(r0 + rw) * B_ + (b0 + f)) * I_;
        *(float4*)d = a0;
        *(float4*)(d + 4) = a1;
    }
}

// spart[ks,c*O+o,b] = sum_{r in chunk} softmax_r(bijT[c,:]) * dot(W[r,c,o,:], xT[r,b,:])
// grid (C_, KS2_), 256 thr = 4 waves.  Wave owns a 4-o tile (W = 32 floats/r
// -> fits SGPR budget, scalar-prefetchable).  Lane owns 4 b's (b = bb*64+lane,
// coalesced).  16 independent acc chains.  Softmax over routes computed
// in-block from bijT.  Atomic-free: partials per ks slice.
template <bool UNIFORM>
__global__ __launch_bounds__(256) void k_s4(const float* __restrict__ xT,
                                            const float* __restrict__ Wm,
                                            const float* __restrict__ bijT,
                                            float* __restrict__ spart) {
    const int tid  = threadIdx.x;
    const int lane = tid & 63;
    const int c    = blockIdx.x;          // 0..9
    const int ks   = blockIdx.y;          // 0..KS2_-1
    const int r0   = ks * RC2_;

    __shared__ float sred[8];

    float bm = 0.f, inv = 1.0f / (float)R_;
    if (!UNIFORM) {
        const float* bc = bijT + (size_t)c * R_;
        float m = -1e30f;
        #pragma unroll
        for (int k = 0; k < 5; ++k) {
            const int r = tid + 256 * k;
            if (r < R_) m = fmaxf(m, bc[r]);
        }
        #pragma unroll
        for (int off = 32; off > 0; off >>= 1)
            m = fmaxf(m, __shfl_down(m, off, 64));
        if (lane == 0) sred[tid >> 6] = m;
        __syncthreads();
        bm = fmaxf(fmaxf(sred[0], sred[1]), fmaxf(sred[2], sred[3]));

        float se = 0.f;
        #pragma unroll
        for (int k = 0; k < 5; ++k) {
            const int r = tid + 256 * k;
            if (r < R_) se += expf(bc[r] - bm);
        }
        #pragma unroll
        for (int off = 32; off > 0; off >>= 1)
            se += __shfl_down(se, off, 64);
        if (lane == 0) sred[4 + (tid >> 6)] = se;
        __syncthreads();
        inv = 1.0f / (sred[4] + sred[5] + sred[6] + sred[7]);
    }

    // wave-uniform o-tile base (forced scalar)
    const int o0 = __builtin_amdgcn_readfirstlane((tid >> 6) * 4);

    float acc[4][4];                      // [oo][bb]
    #pragma unroll
    for (int oo = 0; oo < 4; ++oo)
        #pragma unroll
        for (int bb = 0; bb < 4; ++bb) acc[oo][bb] = 0.f;

    const float* xbase = xT + ((size_t)r0 * B_ + lane) * I_;
    const float* wp    = Wm + (((size_t)r0 * C_ + c) * O_ + o0) * I_;
    const float* bcr   = bijT + (size_t)c * R_ + r0;

    #pragma unroll 2
    for (int r = 0; r < RC2_; ++r) {
        // x fragments: 4 b's, coalesced (lane-stride 32 B)
        float4 xa[4][2];
        #pragma unroll
        for (int bb = 0; bb < 4; ++bb) {
            const float4* xp = (const float4*)(xbase + (size_t)r * B_ * I_ + bb * 64 * I_);
            xa[bb][0] = xp[0];
            xa[bb][1] = xp[1];
        }
        // W fragment: 32 floats, wave-uniform -> scalar loads
        float w[4][8];
        #pragma unroll
        for (int oo = 0; oo < 4; ++oo) {
            const float4 w0 = *(const float4*)(wp + oo * 8);
            const float4 w1 = *(const float4*)(wp + oo * 8 + 4);
            w[oo][0] = w0.x; w[oo][1] = w0.y; w[oo][2] = w0.z; w[oo][3] = w0.w;
            w[oo][4] = w1.x; w[oo][5] = w1.y; w[oo][6] = w1.z; w[oo][7] = w1.w;
        }
        const float cw = UNIFORM ? (1.0f / (float)R_) : expf(bcr[r] - bm) * inv;

        #pragma unroll
        for (int oo = 0; oo < 4; ++oo) {
            #pragma unroll
            for (int bb = 0; bb < 4; ++bb) {
                const float p0 = fmaf(xa[bb][0].y, w[oo][1], xa[bb][0].x * w[oo][0]);
                const float p1 = fmaf(xa[bb][0].w, w[oo][3], xa[bb][0].z * w[oo][2]);
                const float p2 = fmaf(xa[bb][1].y, w[oo][5], xa[bb][1].x * w[oo][4]);
                const float p3 = fmaf(xa[bb][1].w, w[oo][7], xa[bb][1].z * w[oo][6]);
                acc[oo][bb] = fmaf(cw, (p0 + p1) + (p2 + p3), acc[oo][bb]);
            }
        }
        wp += WRI_;
    }

    // store: spart[ks][c*O + o0+oo][bb*64 + lane]  (lane-contiguous)
    float* sp = spart + ((size_t)ks * CO_ + (size_t)c * O_ + o0) * B_ + lane;
    #pragma unroll
    for (int oo = 0; oo < 4; ++oo)
        #pragma unroll
        for (int bb = 0; bb < 4; ++bb)
            sp[(size_t)oo * B_ + bb * 64] = acc[oo][bb];
}

// vout[b,co] = squash(sum_ks spart[ks,co,b]).  grid CO_, 256 thr.
__global__ __launch_bounds__(256) void k_v2(const float* __restrict__ spart,
                                            float* __restrict__ vout) {
    const int b  = threadIdx.x;
    const int co = blockIdx.x;
    const float* p = spart + (size_t)co * B_ + b;
    float s0 = 0.f, s1 = 0.f, s2 = 0.f, s3 = 0.f;
    #pragma unroll
    for (int k = 0; k < KS2_; k += 4) {
        s0 += p[(size_t)(k + 0) * CO_ * B_];
        s1 += p[(size_t)(k + 1) * CO_ * B_];
        s2 += p[(size_t)(k + 2) * CO_ * B_];
        s3 += p[(size_t)(k + 3) * CO_ * B_];
    }
    vout[(size_t)b * CO_ + co] = squashf((s0 + s1) + (s2 + s3));
}

// bijT[c, r0+rr] += (1/B) sum_o sum_i W[r,c,o,i] * (sum_b v[b,c,o]*xT[r,b,i])
// grid R_/RT_ blocks, 640 thr = 160 co x 4 b-groups of 64.
__global__ __launch_bounds__(640) void k_a4(const float* __restrict__ xT,
                                            const float* __restrict__ Wm,
                                            const float* __restrict__ v,
                                            float* __restrict__ bijT) {
    __shared__ __align__(16) float xrow[RT_ * B_ * I_];   // 32 KB
    __shared__ float part[RT_][640];                      // 10 KB

    const int tid = threadIdx.x;
    const int r0  = blockIdx.x * RT_;

    for (int k = tid; k < RT_ * B_ * I_ / 4; k += 640)
        ((float4*)xrow)[k] = ((const float4*)(xT + (size_t)r0 * B_ * I_))[k];
    __syncthreads();

    const int co = tid % CO_;
    const int bg = tid / CO_;           // 0..3
    const int b0 = bg * 64;

    float acc[RT_][8];
    #pragma unroll
    for (int rr = 0; rr < RT_; ++rr)
        #pragma unroll
        for (int i = 0; i < 8; ++i) acc[rr][i] = 0.f;

    const float* vp = v + co;
    #pragma unroll 2
    for (int bb = 0; bb < 64; ++bb) {
        const int b = b0 + bb;
        const float vt = vp[(size_t)b * CO_];
        #pragma unroll
        for (int rr = 0; rr < RT_; ++rr) {
            const float4 y0 = *(const float4*)(&xrow[(rr * B_ + b) * I_]);
            const float4 y1 = *(const float4*)(&xrow[(rr * B_ + b) * I_ + 4]);
            acc[rr][0] = fmaf(vt, y0.x, acc[rr][0]);
            acc[rr][1] = fmaf(vt, y0.y, acc[rr][1]);
            acc[rr][2] = fmaf(vt, y0.z, acc[rr][2]);
            acc[rr][3] = fmaf(vt, y0.w, acc[rr][3]);
            acc[rr][4] = fmaf(vt, y1.x, acc[rr][4]);
            acc[rr][5] = fmaf(vt, y1.y, acc[rr][5]);
            acc[rr][6] = fmaf(vt, y1.z, acc[rr][6]);
            acc[rr][7] = fmaf(vt, y1.w, acc[rr][7]);
        }
    }

    #pragma unroll
    for (int rr = 0; rr < RT_; ++rr) {
        const float* wp = Wm + (((size_t)(r0 + rr)) * CO_ + co) * I_;
        const float4 w0 = *(const float4*)wp;
        const float4 w1 = *(const float4*)(wp + 4);
        const float p0 = fmaf(acc[rr][1], w0.y, acc[rr][0] * w0.x);
        const float p1 = fmaf(acc[rr][3], w0.w, acc[rr][2] * w0.z);
        const float p2 = fmaf(acc[rr][5], w1.y, acc[rr][4] * w1.x);
        const float p3 = fmaf(acc[rr][7], w1.w, acc[rr][6] * w1.z);
        part[rr][tid] = (p0 + p1) + (p2 + p3);
    }
    __syncthreads();

    if (tid < CO_) {
        #pragma unroll
        for (int rr = 0; rr < RT_; ++rr) {
            float a = part[rr][tid] + part[rr][CO_ + tid] +
                      part[rr][2 * CO_ + tid] + part[rr][3 * CO_ + tid];
            #pragma unroll
            for (int off = 8; off > 0; off >>= 1)
                a += __shfl_down(a, off, 16);
            if ((tid & 15) == 0)
                bijT[(size_t)(tid >> 4) * R_ + (r0 + rr)] += a * (1.0f / (float)B_);
        }
    }
}

// ===========================================================================
// FALLBACK PATH (used only if ws is too small for xT)
// ===========================================================================

template <bool UNIFORM>
__global__ __launch_bounds__(256) void k_s_f(const float* __restrict__ x,
                                             const float* __restrict__ Wm,
                                             const float* __restrict__ cij,
                                             float* __restrict__ s_out) {
    const int o  = threadIdx.x & 15;
    const int tb = threadIdx.x >> 4;
    const int b  = blockIdx.z * MBF_ + tb;
    const int c  = blockIdx.y;
    const int r0 = blockIdx.x * RCF_;

    const float* xp = x + ((size_t)b * R_ + r0) * I_;
    const float* wp = Wm + (((size_t)r0 * C_ + c) * O_ + o) * I_;
    const float* cp = cij + (size_t)r0 * C_ + c;

    float acc = 0.f;
    #pragma unroll 4
    for (int r = 0; r < RCF_; ++r) {
        const float4 xv0 = *(const float4*)(xp);
        const float4 xv1 = *(const float4*)(xp + 4);
        const float4 wv0 = *(const float4*)(wp);
        const float4 wv1 = *(const float4*)(wp + 4);
        const float p0 = fmaf(xv0.y, wv0.y, xv0.x * wv0.x);
        const float p1 = fmaf(xv0.w, wv0.w, xv0.z * wv0.z);
        const float p2 = fmaf(xv1.y, wv1.y, xv1.x * wv1.x);
        const float p3 = fmaf(xv1.w, wv1.w, xv1.z * wv1.z);
        const float cw = UNIFORM ? (1.0f / (float)R_) : cp[0];
        acc = fmaf(cw, (p0 + p1) + (p2 + p3), acc);
        xp += I_;
        wp += WRI_;
        cp += C_;
    }
    atomicAdd(&s_out[((size_t)b * C_ + c) * O_ + o], acc);
}

__global__ __launch_bounds__(256) void k_a_f(const float* __restrict__ x,
                                             const float* __restrict__ Wm,
                                             const float* __restrict__ s_in,
                                             float* __restrict__ amean) {
    __shared__ __align__(16) float wlds[2 * WRI_];
    __shared__ float red[4][2 * C_];

    const int tid = threadIdx.x;
    const int r0  = blockIdx.x * 2;

    const float* wsrc = Wm + (size_t)r0 * WRI_;
    #pragma unroll
    for (int k = 0; k < 2 * WRI_ / 256; ++k)
        wlds[tid + 256 * k] = wsrc[tid + 256 * k];
    __syncthreads();

    const int b    = tid;
    const int lane = tid & 63;
    const int wv   = tid >> 6;

    float xv[2][I_];
    const float4* xp4 = (const float4*)(x + ((size_t)b * R_ + r0) * I_);
    #pragma unroll
    for (int rr = 0; rr < 2; ++rr) {
        const float4 a0 = xp4[rr * 2 + 0];
        const float4 a1 = xp4[rr * 2 + 1];
        xv[rr][0] = a0.x; xv[rr][1] = a0.y; xv[rr][2] = a0.z; xv[rr][3] = a0.w;
        xv[rr][4] = a1.x; xv[rr][5] = a1.y; xv[rr][6] = a1.z; xv[rr][7] = a1.w;
    }

    #pragma unroll 1
    for (int c = 0; c < C_; ++c) {
        const float4* sp4 = (const float4*)(s_in + ((size_t)b * C_ + c) * O_);
        float v[O_];
        #pragma unroll
        for (int q = 0; q < 4; ++q) {
            const float4 sv = sp4[q];
            v[q * 4 + 0] = squashf(sv.x);
            v[q * 4 + 1] = squashf(sv.y);
            v[q * 4 + 2] = squashf(sv.z);
            v[q * 4 + 3] = squashf(sv.w);
        }
        #pragma unroll 1
        for (int rr = 0; rr < 2; ++rr) {
            const float4* wl4 = (const float4*)&wlds[(rr * C_ + c) * O_ * I_];
            float a = 0.f;
            #pragma unroll
            for (int o = 0; o < O_; ++o) {
                const float4 w0 = wl4[o * 2 + 0];
                const float4 w1 = wl4[o * 2 + 1];
                float u = xv[rr][0] * w0.x;
                u = fmaf(xv[rr][1], w0.y, u);
                u = fmaf(xv[rr][2], w0.z, u);
                u = fmaf(xv[rr][3], w0.w, u);
                u = fmaf(xv[rr][4], w1.x, u);
                u = fmaf(xv[rr][5], w1.y, u);
                u = fmaf(xv[rr][6], w1.z, u);
                u = fmaf(xv[rr][7], w1.w, u);
                a = fmaf(u, v[o], a);
            }
            #pragma unroll
            for (int off = 32; off > 0; off >>= 1)
                a += __shfl_down(a, off, 64);
            if (lane == 0) red[wv][rr * C_ + c] = a;
        }
    }

    __syncthreads();
    if (tid < 2 * C_) {
        const float t = red[0][tid] + red[1][tid] + red[2][tid] + red[3][tid];
        const int rr = tid / C_;
        const int c  = tid % C_;
        amean[(size_t)(r0 + rr) * C_ + c] = t * (1.0f / (float)B_);
    }
}

__global__ __launch_bounds__(256) void k_soft(const float* __restrict__ amean,
                                              float* __restrict__ bij,
                                              float* __restrict__ cij) {
    const int c   = blockIdx.x;
    const int tid = threadIdx.x;
    __shared__ float sred[4];

    float vals[5];
    float m = -1e30f;
    #pragma unroll
    for (int k = 0; k < 5; ++k) {
        const int r = tid + 256 * k;
        if (r < R_) {
            const size_t idx = (size_t)r * C_ + c;
            const float vv = bij[idx] + amean[idx];
            bij[idx] = vv;
            vals[k] = vv;
            m = fmaxf(m, vv);
        } else {
            vals[k] = -1e30f;
        }
    }
    #pragma unroll
    for (int off = 32; off > 0; off >>= 1)
        m = fmaxf(m, __shfl_down(m, off, 64));
    if ((tid & 63) == 0) sred[tid >> 6] = m;
    __syncthreads();
    const float bm = fmaxf(fmaxf(sred[0], sred[1]), fmaxf(sred[2], sred[3]));
    __syncthreads();

    float se = 0.f;
    #pragma unroll
    for (int k = 0; k < 5; ++k)
        se += (vals[k] > -1e29f) ? expf(vals[k] - bm) : 0.f;
    #pragma unroll
    for (int off = 32; off > 0; off >>= 1)
        se += __shfl_down(se, off, 64);
    if ((tid & 63) == 0) sred[tid >> 6] = se;
    __syncthreads();
    const float inv = 1.0f / (sred[0] + sred[1] + sred[2] + sred[3]);

    #pragma unroll
    for (int k = 0; k < 5; ++k) {
        const int r = tid + 256 * k;
        if (r < R_) cij[(size_t)r * C_ + c] = expf(vals[k] - bm) * inv;
    }
}

__global__ __launch_bounds__(256) void k_squash(float* __restrict__ s) {
    const int idx = blockIdx.x * 256 + threadIdx.x;
    if (idx < B_ * CO_) s[idx] = squashf(s[idx]);
}

} // namespace

extern "C" void kernel_launch(void* const* d_in, const int* in_sizes, int n_in,
                              void* d_out, int out_size, void* d_ws, size_t ws_size,
                              hipStream_t stream) {
    const float* x  = (const float*)d_in[0];   // [256,1152,8]
    const float* Wm = (const float*)d_in[1];   // [1152,10,16,8]
    float* out = (float*)d_out;                // [256,10,16] flat = 40960
    float* ws  = (float*)d_ws;

    const size_t XT_N    = (size_t)R_ * B_ * I_;        // 2,359,296 floats
    const size_t SPART_N = (size_t)KS2_ * CO_ * B_;     // 2,621,440 floats
    const size_t need_floats =
        XT_N + SPART_N + (size_t)(B_ * CO_) + (size_t)(C_ * R_);

    if (ws_size >= need_floats * sizeof(float)) {
        // ---------------- fast path ----------------
        float* xT    = ws;
        float* spart = xT + XT_N;                 // [KS2_][CO_][B_]
        float* v     = spart + SPART_N;           // [B_][CO_]
        float* bijT  = v + (size_t)B_ * CO_;      // [C_][R_]

        k_tr<<<1152, 256, 0, stream>>>(x, xT);
        hipMemsetAsync(bijT, 0, C_ * R_ * sizeof(float), stream);

        const dim3 gs(C_, KS2_);                  // 640 blocks

        // iter 0 (uniform weights; softmax(0) == 1/R)
        k_s4<true><<<gs, 256, 0, stream>>>(xT, Wm, bijT, spart);
        k_v2<<<CO_, B_, 0, stream>>>(spart, v);
        k_a4<<<R_ / RT_, 640, 0, stream>>>(xT, Wm, v, bijT);

        // iter 1 (softmax of bij computed inside k_s4)
        k_s4<false><<<gs, 256, 0, stream>>>(xT, Wm, bijT, spart);
        k_v2<<<CO_, B_, 0, stream>>>(spart, v);
        k_a4<<<R_ / RT_, 640, 0, stream>>>(xT, Wm, v, bijT);

        // iter 2: final v straight into d_out
        k_s4<false><<<gs, 256, 0, stream>>>(xT, Wm, bijT, spart);
        k_v2<<<CO_, B_, 0, stream>>>(spart, out);
    } else {
        // ---------------- fallback ----------------
        float* s_buf = ws;
        float* cij   = ws + 40960;
        float* bij   = cij + R_ * C_;
        float* amean = bij + R_ * C_;

        const dim3 gs(KSF_, C_, B_ / MBF_);

        hipMemsetAsync(bij, 0, R_ * C_ * sizeof(float), stream);

        hipMemsetAsync(s_buf, 0, B_ * CO_ * sizeof(float), stream);
        k_s_f<true><<<gs, 256, 0, stream>>>(x, Wm, cij, s_buf);
        k_a_f<<<R_ / 2, 256, 0, stream>>>(x, Wm, s_buf, amean);
        k_soft<<<C_, 256, 0, stream>>>(amean, bij, cij);

        hipMemsetAsync(s_buf, 0, B_ * CO_ * sizeof(float), stream);
        k_s_f<false><<<gs, 256, 0, stream>>>(x, Wm, cij, s_buf);
        k_a_f<<<R_ / 2, 256, 0, stream>>>(x, Wm, s_buf, amean);
        k_soft<<<C_, 256, 0, stream>>>(amean, bij, cij);

        hipMemsetAsync(out, 0, B_ * CO_ * sizeof(float), stream);
        k_s_f<false><<<gs, 256, 0, stream>>>(x, Wm, cij, out);
        k_squash<<<(B_ * CO_ + 255) / 256, 256, 0, stream>>>(out);
    }
}

// Round 7
// 221.419 us; speedup vs baseline: 1.3166x; 1.0031x over previous
//
#include <hip/hip_runtime.h>
#include <math.h>

namespace {

constexpr int B_ = 256;
constexpr int R_ = 1152;
constexpr int C_ = 10;
constexpr int O_ = 16;
constexpr int I_ = 8;
constexpr int CO_ = C_ * O_;          // 160
constexpr int WRI_ = C_ * O_ * I_;    // 1280 floats of W per route

constexpr int NBLK_ = 640;            // fused-kernel grid (<= 3 blocks/CU * 256 CU)
constexpr int KS2_ = 64;              // r-splits in P1 / k_s4
constexpr int RC2_ = R_ / KS2_;       // 18 routes per block
constexpr int RT_  = 4;               // routes per k_a4 block (fallback)

// fallback tier-3 params
constexpr int KSF_ = 16;
constexpr int RCF_ = R_ / KSF_;       // 72
constexpr int MBF_ = 16;

// fused ws layout (float offsets)
constexpr size_t XT_OFF    = 0;                          // [R][B][I]
constexpr size_t XT_N      = (size_t)R_ * B_ * I_;       // 2,359,296
constexpr size_t SP_OFF    = XT_OFF + XT_N;              // [CO][KS2][B]
constexpr size_t SP_N      = (size_t)CO_ * KS2_ * B_;    // 2,621,440
constexpr size_t V_OFF     = SP_OFF + SP_N;              // [B][CO]
constexpr size_t V_N       = (size_t)B_ * CO_;           // 40,960
constexpr size_t BIJ_OFF   = V_OFF + V_N;                // [C][R]
constexpr size_t BIJ_N     = (size_t)C_ * R_;            // 11,520
constexpr size_t FL_TOTAL  = BIJ_OFF + BIJ_N;            // 5,033,216 floats

__device__ __forceinline__ float squashf(float s) {
    // faithful to reference: s^2*s/((1+s^2)*sqrt(s^2)) == s*|s|/(1+s^2)
    return s * fabsf(s) / (1.0f + s * s);
}

// ---------------------------------------------------------------------------
// software grid barrier: all NBLK_ blocks co-resident (launch_bounds-enforced)
// __threadfence() at agent scope emits buffer_wbl2/buffer_inv sc1 on gfx950
// -> plain stores/loads are cross-XCD coherent across this barrier.
// ---------------------------------------------------------------------------
__device__ __forceinline__ void gbar(unsigned* bar) {
    __syncthreads();
    if (threadIdx.x == 0) {
        __threadfence();   // release: flush L1/L2 to coherent point
        const unsigned gen =
            __hip_atomic_load(&bar[1], __ATOMIC_RELAXED, __HIP_MEMORY_SCOPE_AGENT);
        const unsigned prev =
            __hip_atomic_fetch_add(&bar[0], 1u, __ATOMIC_ACQ_REL, __HIP_MEMORY_SCOPE_AGENT);
        if (prev == (unsigned)NBLK_ - 1u) {
            __hip_atomic_store(&bar[0], 0u, __ATOMIC_RELAXED, __HIP_MEMORY_SCOPE_AGENT);
            __hip_atomic_store(&bar[1], gen + 1u, __ATOMIC_RELEASE, __HIP_MEMORY_SCOPE_AGENT);
        } else {
            unsigned spins = 0;
            while (__hip_atomic_load(&bar[1], __ATOMIC_ACQUIRE,
                                     __HIP_MEMORY_SCOPE_AGENT) == gen) {
                __builtin_amdgcn_s_sleep(4);
                if (++spins > 2000000u) break;   // hang guard: fail visibly, not forever
            }
        }
        __threadfence();   // acquire: invalidate L1/L2 before post-barrier reads
    }
    __syncthreads();
}

// ===========================================================================
// FUSED persistent kernel: transpose + 3 routing iterations, 8 grid syncs
// ===========================================================================
__global__ __launch_bounds__(256, 3) void k_fused(const float* __restrict__ x,
                                                  const float* __restrict__ Wm,
                                                  float* __restrict__ xT,
                                                  float* __restrict__ spart,
                                                  float* __restrict__ v,
                                                  float* __restrict__ bijT,
                                                  unsigned* __restrict__ bar,
                                                  float* __restrict__ out) {
    __shared__ float sh[4160];   // 16.25 KB union: P0 tile / P1 red+cw / P2 red / P3 xrow

    const int blk  = blockIdx.x;
    const int tid  = threadIdx.x;
    const int lane = tid & 63;

    // ---------------- P0: zero bij + transpose x -> xT ----------------
    {
        const int gi = blk * 256 + tid;
        if (gi < C_ * R_) bijT[gi] = 0.f;
    }
    for (int t = blk; t < 1152; t += NBLK_) {
        const int r0 = (t % 36) * 32, b0 = (t / 36) * 8;
        {
            const int rl = tid & 31, bl = tid >> 5;
            const float4* p =
                (const float4*)(x + ((size_t)(b0 + bl) * R_ + (r0 + rl)) * I_);
            const float4 a0 = p[0], a1 = p[1];
            float* d = &sh[(bl * 32 + rl) * 8];
            *(float4*)d = a0;
            *(float4*)(d + 4) = a1;
        }
        __syncthreads();
        {
            const int f = tid & 7, rw = tid >> 3;
            const float* s8 = &sh[(f * 32 + rw) * 8];
            const float4 a0 = *(const float4*)s8, a1 = *(const float4*)(s8 + 4);
            float* d = xT + ((size_t)(r0 + rw) * B_ + (b0 + f)) * I_;
            *(float4*)d = a0;
            *(float4*)(d + 4) = a1;
        }
        __syncthreads();
    }
    gbar(bar);

    const int c  = blk % C_;                 // P1 mapping
    const int ks = blk / C_;
    const int r0s = ks * RC2_;
    const int o0 = __builtin_amdgcn_readfirstlane((tid >> 6) * 4);

    for (int it = 0; it < 3; ++it) {
        // ---------------- P1: split-K s-partials (k_s4 structure) ----------------
        {
            if (it > 0) {
                // softmax stats over routes for this block's capsule c
                const float* bc = bijT + (size_t)c * R_;
                float m = -1e30f;
                #pragma unroll
                for (int k = 0; k < 5; ++k) {
                    const int r = tid + 256 * k;
                    if (r < R_) m = fmaxf(m, bc[r]);
                }
                #pragma unroll
                for (int off = 32; off > 0; off >>= 1)
                    m = fmaxf(m, __shfl_down(m, off, 64));
                if (lane == 0) sh[tid >> 6] = m;
                __syncthreads();
                const float bm = fmaxf(fmaxf(sh[0], sh[1]), fmaxf(sh[2], sh[3]));
                float se = 0.f;
                #pragma unroll
                for (int k = 0; k < 5; ++k) {
                    const int r = tid + 256 * k;
                    if (r < R_) se += expf(bc[r] - bm);
                }
                #pragma unroll
                for (int off = 32; off > 0; off >>= 1)
                    se += __shfl_down(se, off, 64);
                if (lane == 0) sh[4 + (tid >> 6)] = se;
                __syncthreads();
                const float inv = 1.0f / (sh[4] + sh[5] + sh[6] + sh[7]);
                // cache the 18 per-route weights for this chunk
                if (tid < RC2_) sh[8 + tid] = expf(bc[r0s + tid] - bm) * inv;
                __syncthreads();
            }

            float acc[4][4];
            #pragma unroll
            for (int oo = 0; oo < 4; ++oo)
                #pragma unroll
                for (int bb = 0; bb < 4; ++bb) acc[oo][bb] = 0.f;

            const float* xbase = xT + ((size_t)r0s * B_ + lane) * I_;
            const float* wp = Wm + (((size_t)r0s * C_ + c) * O_ + o0) * I_;

            #pragma unroll 2
            for (int r = 0; r < RC2_; ++r) {
                float4 xa[4][2];
                #pragma unroll
                for (int bb = 0; bb < 4; ++bb) {
                    const float4* xp =
                        (const float4*)(xbase + (size_t)r * B_ * I_ + bb * 64 * I_);
                    xa[bb][0] = xp[0];
                    xa[bb][1] = xp[1];
                }
                float w[4][8];
                #pragma unroll
                for (int oo = 0; oo < 4; ++oo) {
                    const float4 w0 = *(const float4*)(wp + oo * 8);
                    const float4 w1 = *(const float4*)(wp + oo * 8 + 4);
                    w[oo][0] = w0.x; w[oo][1] = w0.y; w[oo][2] = w0.z; w[oo][3] = w0.w;
                    w[oo][4] = w1.x; w[oo][5] = w1.y; w[oo][6] = w1.z; w[oo][7] = w1.w;
                }
                const float cw = (it == 0) ? (1.0f / (float)R_) : sh[8 + r];
                #pragma unroll
                for (int oo = 0; oo < 4; ++oo) {
                    #pragma unroll
                    for (int bb = 0; bb < 4; ++bb) {
                        const float p0 = fmaf(xa[bb][0].y, w[oo][1], xa[bb][0].x * w[oo][0]);
                        const float p1 = fmaf(xa[bb][0].w, w[oo][3], xa[bb][0].z * w[oo][2]);
                        const float p2 = fmaf(xa[bb][1].y, w[oo][5], xa[bb][1].x * w[oo][4]);
                        const float p3 = fmaf(xa[bb][1].w, w[oo][7], xa[bb][1].z * w[oo][6]);
                        acc[oo][bb] = fmaf(cw, (p0 + p1) + (p2 + p3), acc[oo][bb]);
                    }
                }
                wp += WRI_;
            }

            // spart[co][ks][b], co = c*16 + o0+oo, b = bb*64+lane
            float* sp = spart + (((size_t)(c * O_ + o0)) * KS2_ + ks) * B_ + lane;
            #pragma unroll
            for (int oo = 0; oo < 4; ++oo)
                #pragma unroll
                for (int bb = 0; bb < 4; ++bb)
                    sp[(size_t)oo * KS2_ * B_ + bb * 64] = acc[oo][bb];
        }
        gbar(bar);

        // ---------------- P2: v = squash(sum_ks spart) ----------------
        {
            const int co2  = blk % CO_;
            const int bseg = blk / CO_;          // 0..3
            const int g    = tid >> 6;           // ks quarter
            const float* p =
                spart + (((size_t)co2) * KS2_ + g * 16) * B_ + bseg * 64 + lane;
            float t0 = 0.f, t1 = 0.f, t2 = 0.f, t3 = 0.f;
            #pragma unroll
            for (int j = 0; j < 16; j += 4) {
                t0 += p[(size_t)(j + 0) * B_];
                t1 += p[(size_t)(j + 1) * B_];
                t2 += p[(size_t)(j + 2) * B_];
                t3 += p[(size_t)(j + 3) * B_];
            }
            const float s = (t0 + t1) + (t2 + t3);
            if (g) sh[(g - 1) * 64 + lane] = s;
            __syncthreads();
            if (g == 0) {
                const float tot = s + sh[lane] + sh[64 + lane] + sh[128 + lane];
                const float vv = squashf(tot);
                const int b = bseg * 64 + lane;
                v[(size_t)b * CO_ + co2] = vv;
                if (it == 2) out[(size_t)b * CO_ + co2] = vv;
            }
            __syncthreads();
        }
        if (it == 2) break;                      // out fully written; all blocks exit
        gbar(bar);

        // ---------------- P3: agreement -> bijT (+=) ----------------
        if (blk < 576) {
            const int rq = blk >> 1;             // 288 route-quads
            const int bh = blk & 1;              // b half
            const int r0 = rq * 4;

            const float4* src4 = (const float4*)xT;
            float4* sh4 = (float4*)sh;
            #pragma unroll
            for (int k = 0; k < 4; ++k) {
                const int idx = tid + 256 * k;   // 1024 float4 = 4 routes x 128 b
                const int rr = idx >> 8, off = idx & 255;
                sh4[idx] = src4[((size_t)(r0 + rr)) * (B_ * I_ / 4) + bh * 256 + off];
            }
            __syncthreads();

            if (tid < CO_) {
                float acc[4][8];
                #pragma unroll
                for (int rr = 0; rr < 4; ++rr)
                    #pragma unroll
                    for (int i = 0; i < 8; ++i) acc[rr][i] = 0.f;

                const float* vp = v + (size_t)(bh * 128) * CO_ + tid;
                #pragma unroll 2
                for (int bb = 0; bb < 128; ++bb) {
                    const float vt = vp[(size_t)bb * CO_];
                    #pragma unroll
                    for (int rr = 0; rr < 4; ++rr) {
                        const float4 y0 = sh4[rr * 256 + bb * 2];
                        const float4 y1 = sh4[rr * 256 + bb * 2 + 1];
                        acc[rr][0] = fmaf(vt, y0.x, acc[rr][0]);
                        acc[rr][1] = fmaf(vt, y0.y, acc[rr][1]);
                        acc[rr][2] = fmaf(vt, y0.z, acc[rr][2]);
                        acc[rr][3] = fmaf(vt, y0.w, acc[rr][3]);
                        acc[rr][4] = fmaf(vt, y1.x, acc[rr][4]);
                        acc[rr][5] = fmaf(vt, y1.y, acc[rr][5]);
                        acc[rr][6] = fmaf(vt, y1.z, acc[rr][6]);
                        acc[rr][7] = fmaf(vt, y1.w, acc[rr][7]);
                    }
                }
                #pragma unroll
                for (int rr = 0; rr < 4; ++rr) {
                    const float* wp = Wm + (((size_t)(r0 + rr)) * CO_ + tid) * I_;
                    const float4 w0 = *(const float4*)wp;
                    const float4 w1 = *(const float4*)(wp + 4);
                    const float p0 = fmaf(acc[rr][1], w0.y, acc[rr][0] * w0.x);
                    const float p1 = fmaf(acc[rr][3], w0.w, acc[rr][2] * w0.z);
                    const float p2 = fmaf(acc[rr][5], w1.y, acc[rr][4] * w1.x);
                    const float p3 = fmaf(acc[rr][7], w1.w, acc[rr][6] * w1.z);
                    float a = (p0 + p1) + (p2 + p3);
                    #pragma unroll
                    for (int off = 8; off > 0; off >>= 1)
                        a += __shfl_down(a, off, 16);
                    if ((tid & 15) == 0)
                        atomicAdd(&bijT[(size_t)(tid >> 4) * R_ + r0 + rr],
                                  a * (1.0f / (float)B_));
                }
            }
        }
        gbar(bar);
    }
}

// ===========================================================================
// FALLBACK tier 2: round-6 multi-kernel pipeline (proven)
// ===========================================================================
__global__ __launch_bounds__(256) void k_tr(const float* __restrict__ x,
                                            float* __restrict__ xT) {
    __shared__ float t[8][32][8];
    const int r0 = (blockIdx.x % 36) * 32;
    const int b0 = (blockIdx.x / 36) * 8;
    const int tid = threadIdx.x;
    {
        const int rl = tid & 31, bl = tid >> 5;
        const float4* p = (const float4*)(x + ((size_t)(b0 + bl) * R_ + (r0 + rl)) * I_);
        const float4 a0 = p[0], a1 = p[1];
        float* d = &t[bl][rl][0];
        *(float4*)d = a0;
        *(float4*)(d + 4) = a1;
    }
    __syncthreads();
    {
        const int f = tid & 7, rw = tid >> 3;
        const float* s8 = &t[f][rw][0];
        const float4 a0 = *(const float4*)s8, a1 = *(const float4*)(s8 + 4);
        float* d = xT + ((size_t)(r0 + rw) * B_ + (b0 + f)) * I_;
        *(float4*)d = a0;
        *(float4*)(d + 4) = a1;
    }
}

template <bool UNIFORM>
__global__ __launch_bounds__(256) void k_s4(const float* __restrict__ xT,
                                            const float* __restrict__ Wm,
                                            const float* __restrict__ bijT,
                                            float* __restrict__ spart) {
    const int tid  = threadIdx.x;
    const int lane = tid & 63;
    const int c    = blockIdx.x;
    const int ks   = blockIdx.y;
    const int r0   = ks * RC2_;

    __shared__ float sred[8];

    float bm = 0.f, inv = 1.0f / (float)R_;
    if (!UNIFORM) {
        const float* bc = bijT + (size_t)c * R_;
        float m = -1e30f;
        #pragma unroll
        for (int k = 0; k < 5; ++k) {
            const int r = tid + 256 * k;
            if (r < R_) m = fmaxf(m, bc[r]);
        }
        #pragma unroll
        for (int off = 32; off > 0; off >>= 1)
            m = fmaxf(m, __shfl_down(m, off, 64));
        if (lane == 0) sred[tid >> 6] = m;
        __syncthreads();
        bm = fmaxf(fmaxf(sred[0], sred[1]), fmaxf(sred[2], sred[3]));
        float se = 0.f;
        #pragma unroll
        for (int k = 0; k < 5; ++k) {
            const int r = tid + 256 * k;
            if (r < R_) se += expf(bc[r] - bm);
        }
        #pragma unroll
        for (int off = 32; off > 0; off >>= 1)
            se += __shfl_down(se, off, 64);
        if (lane == 0) sred[4 + (tid >> 6)] = se;
        __syncthreads();
        inv = 1.0f / (sred[4] + sred[5] + sred[6] + sred[7]);
    }

    const int o0 = __builtin_amdgcn_readfirstlane((tid >> 6) * 4);

    float acc[4][4];
    #pragma unroll
    for (int oo = 0; oo < 4; ++oo)
        #pragma unroll
        for (int bb = 0; bb < 4; ++bb) acc[oo][bb] = 0.f;

    const float* xbase = xT + ((size_t)r0 * B_ + lane) * I_;
    const float* wp    = Wm + (((size_t)r0 * C_ + c) * O_ + o0) * I_;
    const float* bcr   = bijT + (size_t)c * R_ + r0;

    #pragma unroll 2
    for (int r = 0; r < RC2_; ++r) {
        float4 xa[4][2];
        #pragma unroll
        for (int bb = 0; bb < 4; ++bb) {
            const float4* xp = (const float4*)(xbase + (size_t)r * B_ * I_ + bb * 64 * I_);
            xa[bb][0] = xp[0];
            xa[bb][1] = xp[1];
        }
        float w[4][8];
        #pragma unroll
        for (int oo = 0; oo < 4; ++oo) {
            const float4 w0 = *(const float4*)(wp + oo * 8);
            const float4 w1 = *(const float4*)(wp + oo * 8 + 4);
            w[oo][0] = w0.x; w[oo][1] = w0.y; w[oo][2] = w0.z; w[oo][3] = w0.w;
            w[oo][4] = w1.x; w[oo][5] = w1.y; w[oo][6] = w1.z; w[oo][7] = w1.w;
        }
        const float cw = UNIFORM ? (1.0f / (float)R_) : expf(bcr[r] - bm) * inv;
        #pragma unroll
        for (int oo = 0; oo < 4; ++oo) {
            #pragma unroll
            for (int bb = 0; bb < 4; ++bb) {
                const float p0 = fmaf(xa[bb][0].y, w[oo][1], xa[bb][0].x * w[oo][0]);
                const float p1 = fmaf(xa[bb][0].w, w[oo][3], xa[bb][0].z * w[oo][2]);
                const float p2 = fmaf(xa[bb][1].y, w[oo][5], xa[bb][1].x * w[oo][4]);
                const float p3 = fmaf(xa[bb][1].w, w[oo][7], xa[bb][1].z * w[oo][6]);
                acc[oo][bb] = fmaf(cw, (p0 + p1) + (p2 + p3), acc[oo][bb]);
            }
        }
        wp += WRI_;
    }

    float* sp = spart + (((size_t)(c * O_ + o0)) * KS2_ + ks) * B_ + lane;
    #pragma unroll
    for (int oo = 0; oo < 4; ++oo)
        #pragma unroll
        for (int bb = 0; bb < 4; ++bb)
            sp[(size_t)oo * KS2_ * B_ + bb * 64] = acc[oo][bb];
}

// grid NBLK_: co = blk%CO_, bseg = blk/CO_
template <bool FINAL>
__global__ __launch_bounds__(256) void k_v3(const float* __restrict__ spart,
                                            float* __restrict__ vout) {
    __shared__ float sh[192];
    const int tid  = threadIdx.x;
    const int lane = tid & 63;
    const int g    = tid >> 6;
    const int co2  = blockIdx.x % CO_;
    const int bseg = blockIdx.x / CO_;
    const float* p = spart + (((size_t)co2) * KS2_ + g * 16) * B_ + bseg * 64 + lane;
    float t0 = 0.f, t1 = 0.f, t2 = 0.f, t3 = 0.f;
    #pragma unroll
    for (int j = 0; j < 16; j += 4) {
        t0 += p[(size_t)(j + 0) * B_];
        t1 += p[(size_t)(j + 1) * B_];
        t2 += p[(size_t)(j + 2) * B_];
        t3 += p[(size_t)(j + 3) * B_];
    }
    const float s = (t0 + t1) + (t2 + t3);
    if (g) sh[(g - 1) * 64 + lane] = s;
    __syncthreads();
    if (g == 0) {
        const float tot = s + sh[lane] + sh[64 + lane] + sh[128 + lane];
        const int b = bseg * 64 + lane;
        vout[(size_t)b * CO_ + co2] = squashf(tot);
    }
}

__global__ __launch_bounds__(640) void k_a4(const float* __restrict__ xT,
                                            const float* __restrict__ Wm,
                                            const float* __restrict__ v,
                                            float* __restrict__ bijT) {
    __shared__ __align__(16) float xrow[RT_ * B_ * I_];
    __shared__ float part[RT_][640];

    const int tid = threadIdx.x;
    const int r0  = blockIdx.x * RT_;

    for (int k = tid; k < RT_ * B_ * I_ / 4; k += 640)
        ((float4*)xrow)[k] = ((const float4*)(xT + (size_t)r0 * B_ * I_))[k];
    __syncthreads();

    const int co = tid % CO_;
    const int bg = tid / CO_;
    const int b0 = bg * 64;

    float acc[RT_][8];
    #pragma unroll
    for (int rr = 0; rr < RT_; ++rr)
        #pragma unroll
        for (int i = 0; i < 8; ++i) acc[rr][i] = 0.f;

    const float* vp = v + co;
    #pragma unroll 2
    for (int bb = 0; bb < 64; ++bb) {
        const int b = b0 + bb;
        const float vt = vp[(size_t)b * CO_];
        #pragma unroll
        for (int rr = 0; rr < RT_; ++rr) {
            const float4 y0 = *(const float4*)(&xrow[(rr * B_ + b) * I_]);
            const float4 y1 = *(const float4*)(&xrow[(rr * B_ + b) * I_ + 4]);
            acc[rr][0] = fmaf(vt, y0.x, acc[rr][0]);
            acc[rr][1] = fmaf(vt, y0.y, acc[rr][1]);
            acc[rr][2] = fmaf(vt, y0.z, acc[rr][2]);
            acc[rr][3] = fmaf(vt, y0.w, acc[rr][3]);
            acc[rr][4] = fmaf(vt, y1.x, acc[rr][4]);
            acc[rr][5] = fmaf(vt, y1.y, acc[rr][5]);
            acc[rr][6] = fmaf(vt, y1.z, acc[rr][6]);
            acc[rr][7] = fmaf(vt, y1.w, acc[rr][7]);
        }
    }

    #pragma unroll
    for (int rr = 0; rr < RT_; ++rr) {
        const float* wp = Wm + (((size_t)(r0 + rr)) * CO_ + co) * I_;
        const float4 w0 = *(const float4*)wp;
        const float4 w1 = *(const float4*)(wp + 4);
        const float p0 = fmaf(acc[rr][1], w0.y, acc[rr][0] * w0.x);
        const float p1 = fmaf(acc[rr][3], w0.w, acc[rr][2] * w0.z);
        const float p2 = fmaf(acc[rr][5], w1.y, acc[rr][4] * w1.x);
        const float p3 = fmaf(acc[rr][7], w1.w, acc[rr][6] * w1.z);
        part[rr][tid] = (p0 + p1) + (p2 + p3);
    }
    __syncthreads();

    if (tid < CO_) {
        #pragma unroll
        for (int rr = 0; rr < RT_; ++rr) {
            float a = part[rr][tid] + part[rr][CO_ + tid] +
                      part[rr][2 * CO_ + tid] + part[rr][3 * CO_ + tid];
            #pragma unroll
            for (int off = 8; off > 0; off >>= 1)
                a += __shfl_down(a, off, 16);
            if ((tid & 15) == 0)
                bijT[(size_t)(tid >> 4) * R_ + (r0 + rr)] += a * (1.0f / (float)B_);
        }
    }
}

// ===========================================================================
// FALLBACK tier 3 (tiny ws)
// ===========================================================================
template <bool UNIFORM>
__global__ __launch_bounds__(256) void k_s_f(const float* __restrict__ x,
                                             const float* __restrict__ Wm,
                                             const float* __restrict__ cij,
                                             float* __restrict__ s_out) {
    const int o  = threadIdx.x & 15;
    const int tb = threadIdx.x >> 4;
    const int b  = blockIdx.z * MBF_ + tb;
    const int c  = blockIdx.y;
    const int r0 = blockIdx.x * RCF_;

    const float* xp = x + ((size_t)b * R_ + r0) * I_;
    const float* wp = Wm + (((size_t)r0 * C_ + c) * O_ + o) * I_;
    const float* cp = cij + (size_t)r0 * C_ + c;

    float acc = 0.f;
    #pragma unroll 4
    for (int r = 0; r < RCF_; ++r) {
        const float4 xv0 = *(const float4*)(xp);
        const float4 xv1 = *(const float4*)(xp + 4);
        const float4 wv0 = *(const float4*)(wp);
        const float4 wv1 = *(const float4*)(wp + 4);
        const float p0 = fmaf(xv0.y, wv0.y, xv0.x * wv0.x);
        const float p1 = fmaf(xv0.w, wv0.w, xv0.z * wv0.z);
        const float p2 = fmaf(xv1.y, wv1.y, xv1.x * wv1.x);
        const float p3 = fmaf(xv1.w, wv1.w, xv1.z * wv1.z);
        const float cw = UNIFORM ? (1.0f / (float)R_) : cp[0];
        acc = fmaf(cw, (p0 + p1) + (p2 + p3), acc);
        xp += I_;
        wp += WRI_;
        cp += C_;
    }
    atomicAdd(&s_out[((size_t)b * C_ + c) * O_ + o], acc);
}

__global__ __launch_bounds__(256) void k_a_f(const float* __restrict__ x,
                                             const float* __restrict__ Wm,
                                             const float* __restrict__ s_in,
                                             float* __restrict__ amean) {
    __shared__ __align__(16) float wlds[2 * WRI_];
    __shared__ float red[4][2 * C_];

    const int tid = threadIdx.x;
    const int r0  = blockIdx.x * 2;

    const float* wsrc = Wm + (size_t)r0 * WRI_;
    #pragma unroll
    for (int k = 0; k < 2 * WRI_ / 256; ++k)
        wlds[tid + 256 * k] = wsrc[tid + 256 * k];
    __syncthreads();

    const int b    = tid;
    const int lane = tid & 63;
    const int wv   = tid >> 6;

    float xv[2][I_];
    const float4* xp4 = (const float4*)(x + ((size_t)b * R_ + r0) * I_);
    #pragma unroll
    for (int rr = 0; rr < 2; ++rr) {
        const float4 a0 = xp4[rr * 2 + 0];
        const float4 a1 = xp4[rr * 2 + 1];
        xv[rr][0] = a0.x; xv[rr][1] = a0.y; xv[rr][2] = a0.z; xv[rr][3] = a0.w;
        xv[rr][4] = a1.x; xv[rr][5] = a1.y; xv[rr][6] = a1.z; xv[rr][7] = a1.w;
    }

    #pragma unroll 1
    for (int c = 0; c < C_; ++c) {
        const float4* sp4 = (const float4*)(s_in + ((size_t)b * C_ + c) * O_);
        float v[O_];
        #pragma unroll
        for (int q = 0; q < 4; ++q) {
            const float4 sv = sp4[q];
            v[q * 4 + 0] = squashf(sv.x);
            v[q * 4 + 1] = squashf(sv.y);
            v[q * 4 + 2] = squashf(sv.z);
            v[q * 4 + 3] = squashf(sv.w);
        }
        #pragma unroll 1
        for (int rr = 0; rr < 2; ++rr) {
            const float4* wl4 = (const float4*)&wlds[(rr * C_ + c) * O_ * I_];
            float a = 0.f;
            #pragma unroll
            for (int o = 0; o < O_; ++o) {
                const float4 w0 = wl4[o * 2 + 0];
                const float4 w1 = wl4[o * 2 + 1];
                float u = xv[rr][0] * w0.x;
                u = fmaf(xv[rr][1], w0.y, u);
                u = fmaf(xv[rr][2], w0.z, u);
                u = fmaf(xv[rr][3], w0.w, u);
                u = fmaf(xv[rr][4], w1.x, u);
                u = fmaf(xv[rr][5], w1.y, u);
                u = fmaf(xv[rr][6], w1.z, u);
                u = fmaf(xv[rr][7], w1.w, u);
                a = fmaf(u, v[o], a);
            }
            #pragma unroll
            for (int off = 32; off > 0; off >>= 1)
                a += __shfl_down(a, off, 64);
            if (lane == 0) red[wv][rr * C_ + c] = a;
        }
    }

    __syncthreads();
    if (tid < 2 * C_) {
        const float t = red[0][tid] + red[1][tid] + red[2][tid] + red[3][tid];
        const int rr = tid / C_;
        const int c  = tid % C_;
        amean[(size_t)(r0 + rr) * C_ + c] = t * (1.0f / (float)B_);
    }
}

__global__ __launch_bounds__(256) void k_soft(const float* __restrict__ amean,
                                              float* __restrict__ bij,
                                              float* __restrict__ cij) {
    const int c   = blockIdx.x;
    const int tid = threadIdx.x;
    __shared__ float sred[4];

    float vals[5];
    float m = -1e30f;
    #pragma unroll
    for (int k = 0; k < 5; ++k) {
        const int r = tid + 256 * k;
        if (r < R_) {
            const size_t idx = (size_t)r * C_ + c;
            const float vv = bij[idx] + amean[idx];
            bij[idx] = vv;
            vals[k] = vv;
            m = fmaxf(m, vv);
        } else {
            vals[k] = -1e30f;
        }
    }
    #pragma unroll
    for (int off = 32; off > 0; off >>= 1)
        m = fmaxf(m, __shfl_down(m, off, 64));
    if ((tid & 63) == 0) sred[tid >> 6] = m;
    __syncthreads();
    const float bm = fmaxf(fmaxf(sred[0], sred[1]), fmaxf(sred[2], sred[3]));
    __syncthreads();

    float se = 0.f;
    #pragma unroll
    for (int k = 0; k < 5; ++k)
        se += (vals[k] > -1e29f) ? expf(vals[k] - bm) : 0.f;
    #pragma unroll
    for (int off = 32; off > 0; off >>= 1)
        se += __shfl_down(se, off, 64);
    if ((tid & 63) == 0) sred[tid >> 6] = se;
    __syncthreads();
    const float inv = 1.0f / (sred[0] + sred[1] + sred[2] + sred[3]);

    #pragma unroll
    for (int k = 0; k < 5; ++k) {
        const int r = tid + 256 * k;
        if (r < R_) cij[(size_t)r * C_ + c] = expf(vals[k] - bm) * inv;
    }
}

__global__ __launch_bounds__(256) void k_squash(float* __restrict__ s) {
    const int idx = blockIdx.x * 256 + threadIdx.x;
    if (idx < B_ * CO_) s[idx] = squashf(s[idx]);
}

} // namespace

extern "C" void kernel_launch(void* const* d_in, const int* in_sizes, int n_in,
                              void* d_out, int out_size, void* d_ws, size_t ws_size,
                              hipStream_t stream) {
    const float* x  = (const float*)d_in[0];   // [256,1152,8]
    const float* Wm = (const float*)d_in[1];   // [1152,10,16,8]
    float* out = (float*)d_out;                // [256,10,16] flat = 40960
    float* ws  = (float*)d_ws;

    const size_t fused_need = FL_TOTAL * sizeof(float) + 2 * sizeof(unsigned);

    // decide fused vs fallback: ws budget + guaranteed co-residency of 640 blocks
    bool fused_ok = (ws_size >= fused_need);
    if (fused_ok) {
        int nb = 0, ncu = 0, dev = 0;
        if (hipGetDevice(&dev) != hipSuccess) fused_ok = false;
        if (fused_ok &&
            hipOccupancyMaxActiveBlocksPerMultiprocessor(&nb, k_fused, 256, 0) != hipSuccess)
            fused_ok = false;
        if (fused_ok &&
            hipDeviceGetAttribute(&ncu, hipDeviceAttributeMultiprocessorCount, dev) != hipSuccess)
            fused_ok = false;
        if (fused_ok && (long long)nb * ncu < NBLK_) fused_ok = false;
    }

    if (fused_ok) {
        float* xT    = ws + XT_OFF;
        float* spart = ws + SP_OFF;
        float* v     = ws + V_OFF;
        float* bijT  = ws + BIJ_OFF;
        unsigned* bar = (unsigned*)(ws + FL_TOTAL);

        hipMemsetAsync(bar, 0, 2 * sizeof(unsigned), stream);
        k_fused<<<NBLK_, 256, 0, stream>>>(x, Wm, xT, spart, v, bijT, bar, out);
        return;
    }

    const size_t t2_need =
        (XT_N + SP_N + V_N + BIJ_N) * sizeof(float);

    if (ws_size >= t2_need) {
        // ---------------- tier 2: round-6 pipeline ----------------
        float* xT    = ws + XT_OFF;
        float* spart = ws + SP_OFF;
        float* v     = ws + V_OFF;
        float* bijT  = ws + BIJ_OFF;

        k_tr<<<1152, 256, 0, stream>>>(x, xT);
        hipMemsetAsync(bijT, 0, C_ * R_ * sizeof(float), stream);

        const dim3 gs(C_, KS2_);

        k_s4<true><<<gs, 256, 0, stream>>>(xT, Wm, bijT, spart);
        k_v3<false><<<NBLK_, 256, 0, stream>>>(spart, v);
        k_a4<<<R_ / RT_, 640, 0, stream>>>(xT, Wm, v, bijT);

        k_s4<false><<<gs, 256, 0, stream>>>(xT, Wm, bijT, spart);
        k_v3<false><<<NBLK_, 256, 0, stream>>>(spart, v);
        k_a4<<<R_ / RT_, 640, 0, stream>>>(xT, Wm, v, bijT);

        k_s4<false><<<gs, 256, 0, stream>>>(xT, Wm, bijT, spart);
        k_v3<true><<<NBLK_, 256, 0, stream>>>(spart, out);
    } else {
        // ---------------- tier 3 ----------------
        float* s_buf = ws;
        float* cij   = ws + 40960;
        float* bij   = cij + R_ * C_;
        float* amean = bij + R_ * C_;

        const dim3 gs(KSF_, C_, B_ / MBF_);

        hipMemsetAsync(bij, 0, R_ * C_ * sizeof(float), stream);

        hipMemsetAsync(s_buf, 0, B_ * CO_ * sizeof(float), stream);
        k_s_f<true><<<gs, 256, 0, stream>>>(x, Wm, cij, s_buf);
        k_a_f<<<R_ / 2, 256, 0, stream>>>(x, Wm, s_buf, amean);
        k_soft<<<C_, 256, 0, stream>>>(amean, bij, cij);

        hipMemsetAsync(s_buf, 0, B_ * CO_ * sizeof(float), stream);
        k_s_f<false><<<gs, 256, 0, stream>>>(x, Wm, cij, s_buf);
        k_a_f<<<R_ / 2, 256, 0, stream>>>(x, Wm, s_buf, amean);
        k_soft<<<C_, 256, 0, stream>>>(amean, bij, cij);

        hipMemsetAsync(out, 0, B_ * CO_ * sizeof(float), stream);
        k_s_f<false><<<gs, 256, 0, stream>>>(x, Wm, cij, out);
        k_squash<<<(B_ * CO_ + 255) / 256, 256, 0, stream>>>(out);
    }
}

// Round 8
// 220.981 us; speedup vs baseline: 1.3192x; 1.0020x over previous
//
#include <hip/hip_runtime.h>
#include <math.h>

namespace {

constexpr int B_ = 256;
constexpr int R_ = 1152;
constexpr int C_ = 10;
constexpr int O_ = 16;
constexpr int I_ = 8;
constexpr int CO_ = C_ * O_;          // 160
constexpr int WRI_ = C_ * O_ * I_;    // 1280 floats of W per route

constexpr int NBLK_ = 640;            // fused-kernel grid
constexpr int KS2_ = 64;              // r-splits in P1 / k_s4
constexpr int RC2_ = R_ / KS2_;       // 18 routes per block
constexpr int RT_  = 4;               // routes per k_a4 block (fallback)

// fallback tier-3 params
constexpr int KSF_ = 16;
constexpr int RCF_ = R_ / KSF_;       // 72
constexpr int MBF_ = 16;

// fused ws layout (float offsets)
constexpr size_t XT_OFF    = 0;                          // [R][B][I]
constexpr size_t XT_N      = (size_t)R_ * B_ * I_;       // 2,359,296
constexpr size_t SP_OFF    = XT_OFF + XT_N;              // [CO][KS2][B]
constexpr size_t SP_N      = (size_t)CO_ * KS2_ * B_;    // 2,621,440
constexpr size_t V_OFF     = SP_OFF + SP_N;              // [B][CO]
constexpr size_t V_N       = (size_t)B_ * CO_;           // 40,960
constexpr size_t BIJ_OFF   = V_OFF + V_N;                // [C][R]
constexpr size_t BIJ_N     = (size_t)C_ * R_;            // 11,520
constexpr size_t FL_TOTAL  = BIJ_OFF + BIJ_N;            // floats

__device__ __forceinline__ float squashf(float s) {
    // faithful to reference: s^2*s/((1+s^2)*sqrt(s^2)) == s*|s|/(1+s^2)
    return s * fabsf(s) / (1.0f + s * s);
}

// agent-coherent read: global_load with sc bits -> served from the coherent
// point (IC), never from a (possibly stale) non-coherent per-XCD L2 line.
__device__ __forceinline__ float cohload(const float* p) {
    return __hip_atomic_load(p, __ATOMIC_RELAXED, __HIP_MEMORY_SCOPE_AGENT);
}

// ---------------------------------------------------------------------------
// grid barrier, release-only: the RELEASE fetch_add emits buffer_wbl2
// (writeback, lines stay VALID — no L2 invalidate anywhere). Data mutated
// across the barrier is read via cohload(); read-only / write-once data
// (W, xT) keeps plain cached loads.
// ---------------------------------------------------------------------------
__device__ __forceinline__ void gbar(unsigned* bar) {
    __syncthreads();                 // drains each wave's vmcnt before arrival
    if (threadIdx.x == 0) {
        const unsigned gen =
            __hip_atomic_load(&bar[1], __ATOMIC_RELAXED, __HIP_MEMORY_SCOPE_AGENT);
        const unsigned prev =
            __hip_atomic_fetch_add(&bar[0], 1u, __ATOMIC_RELEASE, __HIP_MEMORY_SCOPE_AGENT);
        if (prev == (unsigned)NBLK_ - 1u) {
            __hip_atomic_store(&bar[0], 0u, __ATOMIC_RELAXED, __HIP_MEMORY_SCOPE_AGENT);
            __hip_atomic_store(&bar[1], gen + 1u, __ATOMIC_RELEASE, __HIP_MEMORY_SCOPE_AGENT);
        } else {
            unsigned spins = 0;
            while (__hip_atomic_load(&bar[1], __ATOMIC_RELAXED,
                                     __HIP_MEMORY_SCOPE_AGENT) == gen) {
                __builtin_amdgcn_s_sleep(2);
                if (++spins > 1000000u) break;   // hang guard
            }
        }
    }
    __syncthreads();
}

// ===========================================================================
// FUSED persistent kernel: transpose + 3 routing iterations, 8 grid syncs
// ===========================================================================
__global__ __launch_bounds__(256, 3) void k_fused(const float* __restrict__ x,
                                                  const float* __restrict__ Wm,
                                                  float* __restrict__ xT,
                                                  float* __restrict__ spart,
                                                  float* __restrict__ v,
                                                  float* __restrict__ bijT,
                                                  unsigned* __restrict__ bar,
                                                  float* __restrict__ out) {
    // union: P0 tile(2048) / P1 red+cw(26) / P2 red(192) / P3 xrow(4096)+vbuf(5120)
    __shared__ __align__(16) float sh[9248];

    const int blk  = blockIdx.x;
    const int tid  = threadIdx.x;
    const int lane = tid & 63;

    // ---------------- P0: zero bij + transpose x -> xT ----------------
    {
        const int gi = blk * 256 + tid;
        if (gi < C_ * R_) bijT[gi] = 0.f;
    }
    for (int t = blk; t < 1152; t += NBLK_) {
        const int r0 = (t % 36) * 32, b0 = (t / 36) * 8;
        {
            const int rl = tid & 31, bl = tid >> 5;
            const float4* p =
                (const float4*)(x + ((size_t)(b0 + bl) * R_ + (r0 + rl)) * I_);
            const float4 a0 = p[0], a1 = p[1];
            float* d = &sh[(bl * 32 + rl) * 8];
            *(float4*)d = a0;
            *(float4*)(d + 4) = a1;
        }
        __syncthreads();
        {
            const int f = tid & 7, rw = tid >> 3;
            const float* s8 = &sh[(f * 32 + rw) * 8];
            const float4 a0 = *(const float4*)s8, a1 = *(const float4*)(s8 + 4);
            float* d = xT + ((size_t)(r0 + rw) * B_ + (b0 + f)) * I_;
            *(float4*)d = a0;
            *(float4*)(d + 4) = a1;
        }
        __syncthreads();
    }
    gbar(bar);   // release-wbl2 makes xT / bij zeros IC-visible

    const int c  = blk % C_;                 // P1 mapping
    const int ks = blk / C_;
    const int r0s = ks * RC2_;
    const int o0 = __builtin_amdgcn_readfirstlane((tid >> 6) * 4);

    for (int it = 0; it < 3; ++it) {
        // ---------------- P1: split-K s-partials ----------------
        {
            if (it > 0) {
                // softmax over routes for capsule c (bijT read coherently)
                const float* bc = bijT + (size_t)c * R_;
                float bv[5];
                #pragma unroll
                for (int k = 0; k < 5; ++k) {
                    const int r = tid + 256 * k;
                    bv[k] = (r < R_) ? cohload(&bc[r]) : -1e30f;
                }
                float m = -1e30f;
                #pragma unroll
                for (int k = 0; k < 5; ++k) m = fmaxf(m, bv[k]);
                #pragma unroll
                for (int off = 32; off > 0; off >>= 1)
                    m = fmaxf(m, __shfl_down(m, off, 64));
                if (lane == 0) sh[tid >> 6] = m;
                __syncthreads();
                const float bm = fmaxf(fmaxf(sh[0], sh[1]), fmaxf(sh[2], sh[3]));
                float se = 0.f;
                #pragma unroll
                for (int k = 0; k < 5; ++k)
                    se += (bv[k] > -1e29f) ? expf(bv[k] - bm) : 0.f;
                #pragma unroll
                for (int off = 32; off > 0; off >>= 1)
                    se += __shfl_down(se, off, 64);
                if (lane == 0) sh[4 + (tid >> 6)] = se;
                __syncthreads();
                const float inv = 1.0f / (sh[4] + sh[5] + sh[6] + sh[7]);
                if (tid < RC2_)
                    sh[8 + tid] = expf(cohload(&bc[r0s + tid]) - bm) * inv;
                __syncthreads();
            }

            float acc[4][4];
            #pragma unroll
            for (int oo = 0; oo < 4; ++oo)
                #pragma unroll
                for (int bb = 0; bb < 4; ++bb) acc[oo][bb] = 0.f;

            const float* xbase = xT + ((size_t)r0s * B_ + lane) * I_;
            const float* wp = Wm + (((size_t)r0s * C_ + c) * O_ + o0) * I_;

            #pragma unroll 2
            for (int r = 0; r < RC2_; ++r) {
                float4 xa[4][2];
                #pragma unroll
                for (int bb = 0; bb < 4; ++bb) {
                    const float4* xp =
                        (const float4*)(xbase + (size_t)r * B_ * I_ + bb * 64 * I_);
                    xa[bb][0] = xp[0];
                    xa[bb][1] = xp[1];
                }
                float w[4][8];
                #pragma unroll
                for (int oo = 0; oo < 4; ++oo) {
                    const float4 w0 = *(const float4*)(wp + oo * 8);
                    const float4 w1 = *(const float4*)(wp + oo * 8 + 4);
                    w[oo][0] = w0.x; w[oo][1] = w0.y; w[oo][2] = w0.z; w[oo][3] = w0.w;
                    w[oo][4] = w1.x; w[oo][5] = w1.y; w[oo][6] = w1.z; w[oo][7] = w1.w;
                }
                const float cw = (it == 0) ? (1.0f / (float)R_) : sh[8 + r];
                #pragma unroll
                for (int oo = 0; oo < 4; ++oo) {
                    #pragma unroll
                    for (int bb = 0; bb < 4; ++bb) {
                        const float p0 = fmaf(xa[bb][0].y, w[oo][1], xa[bb][0].x * w[oo][0]);
                        const float p1 = fmaf(xa[bb][0].w, w[oo][3], xa[bb][0].z * w[oo][2]);
                        const float p2 = fmaf(xa[bb][1].y, w[oo][5], xa[bb][1].x * w[oo][4]);
                        const float p3 = fmaf(xa[bb][1].w, w[oo][7], xa[bb][1].z * w[oo][6]);
                        acc[oo][bb] = fmaf(cw, (p0 + p1) + (p2 + p3), acc[oo][bb]);
                    }
                }
                wp += WRI_;
            }

            float* sp = spart + (((size_t)(c * O_ + o0)) * KS2_ + ks) * B_ + lane;
            #pragma unroll
            for (int oo = 0; oo < 4; ++oo)
                #pragma unroll
                for (int bb = 0; bb < 4; ++bb)
                    sp[(size_t)oo * KS2_ * B_ + bb * 64] = acc[oo][bb];
        }
        gbar(bar);

        // ---------------- P2: v = squash(sum_ks spart) ----------------
        {
            const int co2  = blk % CO_;
            const int bseg = blk / CO_;          // 0..3
            const int g    = tid >> 6;           // ks quarter
            const float* p =
                spart + (((size_t)co2) * KS2_ + g * 16) * B_ + bseg * 64 + lane;
            float t0 = 0.f, t1 = 0.f, t2 = 0.f, t3 = 0.f;
            #pragma unroll
            for (int j = 0; j < 16; j += 4) {
                t0 += cohload(&p[(size_t)(j + 0) * B_]);
                t1 += cohload(&p[(size_t)(j + 1) * B_]);
                t2 += cohload(&p[(size_t)(j + 2) * B_]);
                t3 += cohload(&p[(size_t)(j + 3) * B_]);
            }
            const float s = (t0 + t1) + (t2 + t3);
            if (g) sh[(g - 1) * 64 + lane] = s;
            __syncthreads();
            if (g == 0) {
                const float tot = s + sh[lane] + sh[64 + lane] + sh[128 + lane];
                const float vv = squashf(tot);
                const int b = bseg * 64 + lane;
                v[(size_t)b * CO_ + co2] = vv;
                if (it == 2) out[(size_t)b * CO_ + co2] = vv;
            }
            __syncthreads();
        }
        if (it == 2) break;                      // out fully written
        gbar(bar);

        // ---------------- P3: agreement -> bijT (+=) ----------------
        if (blk < 576) {
            const int rq = blk >> 1;             // 288 route-quads
            const int bh = blk & 1;              // b half
            const int r0 = rq * 4;

            const float4* src4 = (const float4*)xT;
            float4* sh4 = (float4*)sh;           // 1024 float4 = 4 routes x 128 b
            float*  vbuf = sh + 4096;            // 5120 floats: [32 b][160 co]
            #pragma unroll
            for (int k = 0; k < 4; ++k) {
                const int idx = tid + 256 * k;
                const int rr = idx >> 8, off = idx & 255;
                sh4[idx] = src4[((size_t)(r0 + rr)) * (B_ * I_ / 4) + bh * 256 + off];
            }

            float acc[4][8];
            #pragma unroll
            for (int rr = 0; rr < 4; ++rr)
                #pragma unroll
                for (int i = 0; i < 8; ++i) acc[rr][i] = 0.f;

            for (int cb = 0; cb < 4; ++cb) {
                __syncthreads();
                // cooperative coherent staging of 32-b v chunk
                #pragma unroll
                for (int k = 0; k < 20; ++k) {
                    const int idx = tid + 256 * k;           // 0..5119
                    const int bl = idx / CO_, co = idx % CO_;
                    vbuf[idx] =
                        cohload(&v[(size_t)(bh * 128 + cb * 32 + bl) * CO_ + co]);
                }
                __syncthreads();
                if (tid < CO_) {
                    #pragma unroll 4
                    for (int bb = 0; bb < 32; ++bb) {
                        const float vt = vbuf[bb * CO_ + tid];
                        const int gb = cb * 32 + bb;
                        #pragma unroll
                        for (int rr = 0; rr < 4; ++rr) {
                            const float4 y0 = sh4[rr * 256 + gb * 2];
                            const float4 y1 = sh4[rr * 256 + gb * 2 + 1];
                            acc[rr][0] = fmaf(vt, y0.x, acc[rr][0]);
                            acc[rr][1] = fmaf(vt, y0.y, acc[rr][1]);
                            acc[rr][2] = fmaf(vt, y0.z, acc[rr][2]);
                            acc[rr][3] = fmaf(vt, y0.w, acc[rr][3]);
                            acc[rr][4] = fmaf(vt, y1.x, acc[rr][4]);
                            acc[rr][5] = fmaf(vt, y1.y, acc[rr][5]);
                            acc[rr][6] = fmaf(vt, y1.z, acc[rr][6]);
                            acc[rr][7] = fmaf(vt, y1.w, acc[rr][7]);
                        }
                    }
                }
            }

            if (tid < CO_) {
                #pragma unroll
                for (int rr = 0; rr < 4; ++rr) {
                    const float* wp = Wm + (((size_t)(r0 + rr)) * CO_ + tid) * I_;
                    const float4 w0 = *(const float4*)wp;
                    const float4 w1 = *(const float4*)(wp + 4);
                    const float p0 = fmaf(acc[rr][1], w0.y, acc[rr][0] * w0.x);
                    const float p1 = fmaf(acc[rr][3], w0.w, acc[rr][2] * w0.z);
                    const float p2 = fmaf(acc[rr][5], w1.y, acc[rr][4] * w1.x);
                    const float p3 = fmaf(acc[rr][7], w1.w, acc[rr][6] * w1.z);
                    float a = (p0 + p1) + (p2 + p3);
                    #pragma unroll
                    for (int off = 8; off > 0; off >>= 1)
                        a += __shfl_down(a, off, 16);
                    if ((tid & 15) == 0)
                        atomicAdd(&bijT[(size_t)(tid >> 4) * R_ + r0 + rr],
                                  a * (1.0f / (float)B_));
                }
            }
        }
        gbar(bar);
    }
}

// ===========================================================================
// FALLBACK tier 2: round-6 multi-kernel pipeline (proven)
// ===========================================================================
__global__ __launch_bounds__(256) void k_tr(const float* __restrict__ x,
                                            float* __restrict__ xT) {
    __shared__ float t[8][32][8];
    const int r0 = (blockIdx.x % 36) * 32;
    const int b0 = (blockIdx.x / 36) * 8;
    const int tid = threadIdx.x;
    {
        const int rl = tid & 31, bl = tid >> 5;
        const float4* p = (const float4*)(x + ((size_t)(b0 + bl) * R_ + (r0 + rl)) * I_);
        const float4 a0 = p[0], a1 = p[1];
        float* d = &t[bl][rl][0];
        *(float4*)d = a0;
        *(float4*)(d + 4) = a1;
    }
    __syncthreads();
    {
        const int f = tid & 7, rw = tid >> 3;
        const float* s8 = &t[f][rw][0];
        const float4 a0 = *(const float4*)s8, a1 = *(const float4*)(s8 + 4);
        float* d = xT + ((size_t)(r0 + rw) * B_ + (b0 + f)) * I_;
        *(float4*)d = a0;
        *(float4*)(d + 4) = a1;
    }
}

template <bool UNIFORM>
__global__ __launch_bounds__(256) void k_s4(const float* __restrict__ xT,
                                            const float* __restrict__ Wm,
                                            const float* __restrict__ bijT,
                                            float* __restrict__ spart) {
    const int tid  = threadIdx.x;
    const int lane = tid & 63;
    const int c    = blockIdx.x;
    const int ks   = blockIdx.y;
    const int r0   = ks * RC2_;

    __shared__ float sred[8];

    float bm = 0.f, inv = 1.0f / (float)R_;
    if (!UNIFORM) {
        const float* bc = bijT + (size_t)c * R_;
        float m = -1e30f;
        #pragma unroll
        for (int k = 0; k < 5; ++k) {
            const int r = tid + 256 * k;
            if (r < R_) m = fmaxf(m, bc[r]);
        }
        #pragma unroll
        for (int off = 32; off > 0; off >>= 1)
            m = fmaxf(m, __shfl_down(m, off, 64));
        if (lane == 0) sred[tid >> 6] = m;
        __syncthreads();
        bm = fmaxf(fmaxf(sred[0], sred[1]), fmaxf(sred[2], sred[3]));
        float se = 0.f;
        #pragma unroll
        for (int k = 0; k < 5; ++k) {
            const int r = tid + 256 * k;
            if (r < R_) se += expf(bc[r] - bm);
        }
        #pragma unroll
        for (int off = 32; off > 0; off >>= 1)
            se += __shfl_down(se, off, 64);
        if (lane == 0) sred[4 + (tid >> 6)] = se;
        __syncthreads();
        inv = 1.0f / (sred[4] + sred[5] + sred[6] + sred[7]);
    }

    const int o0 = __builtin_amdgcn_readfirstlane((tid >> 6) * 4);

    float acc[4][4];
    #pragma unroll
    for (int oo = 0; oo < 4; ++oo)
        #pragma unroll
        for (int bb = 0; bb < 4; ++bb) acc[oo][bb] = 0.f;

    const float* xbase = xT + ((size_t)r0 * B_ + lane) * I_;
    const float* wp    = Wm + (((size_t)r0 * C_ + c) * O_ + o0) * I_;
    const float* bcr   = bijT + (size_t)c * R_ + r0;

    #pragma unroll 2
    for (int r = 0; r < RC2_; ++r) {
        float4 xa[4][2];
        #pragma unroll
        for (int bb = 0; bb < 4; ++bb) {
            const float4* xp = (const float4*)(xbase + (size_t)r * B_ * I_ + bb * 64 * I_);
            xa[bb][0] = xp[0];
            xa[bb][1] = xp[1];
        }
        float w[4][8];
        #pragma unroll
        for (int oo = 0; oo < 4; ++oo) {
            const float4 w0 = *(const float4*)(wp + oo * 8);
            const float4 w1 = *(const float4*)(wp + oo * 8 + 4);
            w[oo][0] = w0.x; w[oo][1] = w0.y; w[oo][2] = w0.z; w[oo][3] = w0.w;
            w[oo][4] = w1.x; w[oo][5] = w1.y; w[oo][6] = w1.z; w[oo][7] = w1.w;
        }
        const float cw = UNIFORM ? (1.0f / (float)R_) : expf(bcr[r] - bm) * inv;
        #pragma unroll
        for (int oo = 0; oo < 4; ++oo) {
            #pragma unroll
            for (int bb = 0; bb < 4; ++bb) {
                const float p0 = fmaf(xa[bb][0].y, w[oo][1], xa[bb][0].x * w[oo][0]);
                const float p1 = fmaf(xa[bb][0].w, w[oo][3], xa[bb][0].z * w[oo][2]);
                const float p2 = fmaf(xa[bb][1].y, w[oo][5], xa[bb][1].x * w[oo][4]);
                const float p3 = fmaf(xa[bb][1].w, w[oo][7], xa[bb][1].z * w[oo][6]);
                acc[oo][bb] = fmaf(cw, (p0 + p1) + (p2 + p3), acc[oo][bb]);
            }
        }
        wp += WRI_;
    }

    float* sp = spart + (((size_t)(c * O_ + o0)) * KS2_ + ks) * B_ + lane;
    #pragma unroll
    for (int oo = 0; oo < 4; ++oo)
        #pragma unroll
        for (int bb = 0; bb < 4; ++bb)
            sp[(size_t)oo * KS2_ * B_ + bb * 64] = acc[oo][bb];
}

template <bool FINAL>
__global__ __launch_bounds__(256) void k_v3(const float* __restrict__ spart,
                                            float* __restrict__ vout) {
    __shared__ float sh[192];
    const int tid  = threadIdx.x;
    const int lane = tid & 63;
    const int g    = tid >> 6;
    const int co2  = blockIdx.x % CO_;
    const int bseg = blockIdx.x / CO_;
    const float* p = spart + (((size_t)co2) * KS2_ + g * 16) * B_ + bseg * 64 + lane;
    float t0 = 0.f, t1 = 0.f, t2 = 0.f, t3 = 0.f;
    #pragma unroll
    for (int j = 0; j < 16; j += 4) {
        t0 += p[(size_t)(j + 0) * B_];
        t1 += p[(size_t)(j + 1) * B_];
        t2 += p[(size_t)(j + 2) * B_];
        t3 += p[(size_t)(j + 3) * B_];
    }
    const float s = (t0 + t1) + (t2 + t3);
    if (g) sh[(g - 1) * 64 + lane] = s;
    __syncthreads();
    if (g == 0) {
        const float tot = s + sh[lane] + sh[64 + lane] + sh[128 + lane];
        const int b = bseg * 64 + lane;
        vout[(size_t)b * CO_ + co2] = squashf(tot);
    }
}

__global__ __launch_bounds__(640) void k_a4(const float* __restrict__ xT,
                                            const float* __restrict__ Wm,
                                            const float* __restrict__ v,
                                            float* __restrict__ bijT) {
    __shared__ __align__(16) float xrow[RT_ * B_ * I_];
    __shared__ float part[RT_][640];

    const int tid = threadIdx.x;
    const int r0  = blockIdx.x * RT_;

    for (int k = tid; k < RT_ * B_ * I_ / 4; k += 640)
        ((float4*)xrow)[k] = ((const float4*)(xT + (size_t)r0 * B_ * I_))[k];
    __syncthreads();

    const int co = tid % CO_;
    const int bg = tid / CO_;
    const int b0 = bg * 64;

    float acc[RT_][8];
    #pragma unroll
    for (int rr = 0; rr < RT_; ++rr)
        #pragma unroll
        for (int i = 0; i < 8; ++i) acc[rr][i] = 0.f;

    const float* vp = v + co;
    #pragma unroll 2
    for (int bb = 0; bb < 64; ++bb) {
        const int b = b0 + bb;
        const float vt = vp[(size_t)b * CO_];
        #pragma unroll
        for (int rr = 0; rr < RT_; ++rr) {
            const float4 y0 = *(const float4*)(&xrow[(rr * B_ + b) * I_]);
            const float4 y1 = *(const float4*)(&xrow[(rr * B_ + b) * I_ + 4]);
            acc[rr][0] = fmaf(vt, y0.x, acc[rr][0]);
            acc[rr][1] = fmaf(vt, y0.y, acc[rr][1]);
            acc[rr][2] = fmaf(vt, y0.z, acc[rr][2]);
            acc[rr][3] = fmaf(vt, y0.w, acc[rr][3]);
            acc[rr][4] = fmaf(vt, y1.x, acc[rr][4]);
            acc[rr][5] = fmaf(vt, y1.y, acc[rr][5]);
            acc[rr][6] = fmaf(vt, y1.z, acc[rr][6]);
            acc[rr][7] = fmaf(vt, y1.w, acc[rr][7]);
        }
    }

    #pragma unroll
    for (int rr = 0; rr < RT_; ++rr) {
        const float* wp = Wm + (((size_t)(r0 + rr)) * CO_ + co) * I_;
        const float4 w0 = *(const float4*)wp;
        const float4 w1 = *(const float4*)(wp + 4);
        const float p0 = fmaf(acc[rr][1], w0.y, acc[rr][0] * w0.x);
        const float p1 = fmaf(acc[rr][3], w0.w, acc[rr][2] * w0.z);
        const float p2 = fmaf(acc[rr][5], w1.y, acc[rr][4] * w1.x);
        const float p3 = fmaf(acc[rr][7], w1.w, acc[rr][6] * w1.z);
        part[rr][tid] = (p0 + p1) + (p2 + p3);
    }
    __syncthreads();

    if (tid < CO_) {
        #pragma unroll
        for (int rr = 0; rr < RT_; ++rr) {
            float a = part[rr][tid] + part[rr][CO_ + tid] +
                      part[rr][2 * CO_ + tid] + part[rr][3 * CO_ + tid];
            #pragma unroll
            for (int off = 8; off > 0; off >>= 1)
                a += __shfl_down(a, off, 16);
            if ((tid & 15) == 0)
                bijT[(size_t)(tid >> 4) * R_ + (r0 + rr)] += a * (1.0f / (float)B_);
        }
    }
}

// ===========================================================================
// FALLBACK tier 3 (tiny ws)
// ===========================================================================
template <bool UNIFORM>
__global__ __launch_bounds__(256) void k_s_f(const float* __restrict__ x,
                                             const float* __restrict__ Wm,
                                             const float* __restrict__ cij,
                                             float* __restrict__ s_out) {
    const int o  = threadIdx.x & 15;
    const int tb = threadIdx.x >> 4;
    const int b  = blockIdx.z * MBF_ + tb;
    const int c  = blockIdx.y;
    const int r0 = blockIdx.x * RCF_;

    const float* xp = x + ((size_t)b * R_ + r0) * I_;
    const float* wp = Wm + (((size_t)r0 * C_ + c) * O_ + o) * I_;
    const float* cp = cij + (size_t)r0 * C_ + c;

    float acc = 0.f;
    #pragma unroll 4
    for (int r = 0; r < RCF_; ++r) {
        const float4 xv0 = *(const float4*)(xp);
        const float4 xv1 = *(const float4*)(xp + 4);
        const float4 wv0 = *(const float4*)(wp);
        const float4 wv1 = *(const float4*)(wp + 4);
        const float p0 = fmaf(xv0.y, wv0.y, xv0.x * wv0.x);
        const float p1 = fmaf(xv0.w, wv0.w, xv0.z * wv0.z);
        const float p2 = fmaf(xv1.y, wv1.y, xv1.x * wv1.x);
        const float p3 = fmaf(xv1.w, wv1.w, xv1.z * wv1.z);
        const float cw = UNIFORM ? (1.0f / (float)R_) : cp[0];
        acc = fmaf(cw, (p0 + p1) + (p2 + p3), acc);
        xp += I_;
        wp += WRI_;
        cp += C_;
    }
    atomicAdd(&s_out[((size_t)b * C_ + c) * O_ + o], acc);
}

__global__ __launch_bounds__(256) void k_a_f(const float* __restrict__ x,
                                             const float* __restrict__ Wm,
                                             const float* __restrict__ s_in,
                                             float* __restrict__ amean) {
    __shared__ __align__(16) float wlds[2 * WRI_];
    __shared__ float red[4][2 * C_];

    const int tid = threadIdx.x;
    const int r0  = blockIdx.x * 2;

    const float* wsrc = Wm + (size_t)r0 * WRI_;
    #pragma unroll
    for (int k = 0; k < 2 * WRI_ / 256; ++k)
        wlds[tid + 256 * k] = wsrc[tid + 256 * k];
    __syncthreads();

    const int b    = tid;
    const int lane = tid & 63;
    const int wv   = tid >> 6;

    float xv[2][I_];
    const float4* xp4 = (const float4*)(x + ((size_t)b * R_ + r0) * I_);
    #pragma unroll
    for (int rr = 0; rr < 2; ++rr) {
        const float4 a0 = xp4[rr * 2 + 0];
        const float4 a1 = xp4[rr * 2 + 1];
        xv[rr][0] = a0.x; xv[rr][1] = a0.y; xv[rr][2] = a0.z; xv[rr][3] = a0.w;
        xv[rr][4] = a1.x; xv[rr][5] = a1.y; xv[rr][6] = a1.z; xv[rr][7] = a1.w;
    }

    #pragma unroll 1
    for (int c = 0; c < C_; ++c) {
        const float4* sp4 = (const float4*)(s_in + ((size_t)b * C_ + c) * O_);
        float v[O_];
        #pragma unroll
        for (int q = 0; q < 4; ++q) {
            const float4 sv = sp4[q];
            v[q * 4 + 0] = squashf(sv.x);
            v[q * 4 + 1] = squashf(sv.y);
            v[q * 4 + 2] = squashf(sv.z);
            v[q * 4 + 3] = squashf(sv.w);
        }
        #pragma unroll 1
        for (int rr = 0; rr < 2; ++rr) {
            const float4* wl4 = (const float4*)&wlds[(rr * C_ + c) * O_ * I_];
            float a = 0.f;
            #pragma unroll
            for (int o = 0; o < O_; ++o) {
                const float4 w0 = wl4[o * 2 + 0];
                const float4 w1 = wl4[o * 2 + 1];
                float u = xv[rr][0] * w0.x;
                u = fmaf(xv[rr][1], w0.y, u);
                u = fmaf(xv[rr][2], w0.z, u);
                u = fmaf(xv[rr][3], w0.w, u);
                u = fmaf(xv[rr][4], w1.x, u);
                u = fmaf(xv[rr][5], w1.y, u);
                u = fmaf(xv[rr][6], w1.z, u);
                u = fmaf(xv[rr][7], w1.w, u);
                a = fmaf(u, v[o], a);
            }
            #pragma unroll
            for (int off = 32; off > 0; off >>= 1)
                a += __shfl_down(a, off, 64);
            if (lane == 0) red[wv][rr * C_ + c] = a;
        }
    }

    __syncthreads();
    if (tid < 2 * C_) {
        const float t = red[0][tid] + red[1][tid] + red[2][tid] + red[3][tid];
        const int rr = tid / C_;
        const int c  = tid % C_;
        amean[(size_t)(r0 + rr) * C_ + c] = t * (1.0f / (float)B_);
    }
}

__global__ __launch_bounds__(256) void k_soft(const float* __restrict__ amean,
                                              float* __restrict__ bij,
                                              float* __restrict__ cij) {
    const int c   = blockIdx.x;
    const int tid = threadIdx.x;
    __shared__ float sred[4];

    float vals[5];
    float m = -1e30f;
    #pragma unroll
    for (int k = 0; k < 5; ++k) {
        const int r = tid + 256 * k;
        if (r < R_) {
            const size_t idx = (size_t)r * C_ + c;
            const float vv = bij[idx] + amean[idx];
            bij[idx] = vv;
            vals[k] = vv;
            m = fmaxf(m, vv);
        } else {
            vals[k] = -1e30f;
        }
    }
    #pragma unroll
    for (int off = 32; off > 0; off >>= 1)
        m = fmaxf(m, __shfl_down(m, off, 64));
    if ((tid & 63) == 0) sred[tid >> 6] = m;
    __syncthreads();
    const float bm = fmaxf(fmaxf(sred[0], sred[1]), fmaxf(sred[2], sred[3]));
    __syncthreads();

    float se = 0.f;
    #pragma unroll
    for (int k = 0; k < 5; ++k)
        se += (vals[k] > -1e29f) ? expf(vals[k] - bm) : 0.f;
    #pragma unroll
    for (int off = 32; off > 0; off >>= 1)
        se += __shfl_down(se, off, 64);
    if ((tid & 63) == 0) sred[tid >> 6] = se;
    __syncthreads();
    const float inv = 1.0f / (sred[0] + sred[1] + sred[2] + sred[3]);

    #pragma unroll
    for (int k = 0; k < 5; ++k) {
        const int r = tid + 256 * k;
        if (r < R_) cij[(size_t)r * C_ + c] = expf(vals[k] - bm) * inv;
    }
}

__global__ __launch_bounds__(256) void k_squash(float* __restrict__ s) {
    const int idx = blockIdx.x * 256 + threadIdx.x;
    if (idx < B_ * CO_) s[idx] = squashf(s[idx]);
}

} // namespace

extern "C" void kernel_launch(void* const* d_in, const int* in_sizes, int n_in,
                              void* d_out, int out_size, void* d_ws, size_t ws_size,
                              hipStream_t stream) {
    const float* x  = (const float*)d_in[0];   // [256,1152,8]
    const float* Wm = (const float*)d_in[1];   // [1152,10,16,8]
    float* out = (float*)d_out;                // [256,10,16] flat = 40960
    float* ws  = (float*)d_ws;

    const size_t fused_need = FL_TOTAL * sizeof(float) + 2 * sizeof(unsigned);

    bool fused_ok = (ws_size >= fused_need);
    if (fused_ok) {
        int nb = 0, ncu = 0, dev = 0;
        if (hipGetDevice(&dev) != hipSuccess) fused_ok = false;
        if (fused_ok &&
            hipOccupancyMaxActiveBlocksPerMultiprocessor(&nb, k_fused, 256, 0) != hipSuccess)
            fused_ok = false;
        if (fused_ok &&
            hipDeviceGetAttribute(&ncu, hipDeviceAttributeMultiprocessorCount, dev) != hipSuccess)
            fused_ok = false;
        if (fused_ok && (long long)nb * ncu < NBLK_) fused_ok = false;
    }

    if (fused_ok) {
        float* xT    = ws + XT_OFF;
        float* spart = ws + SP_OFF;
        float* v     = ws + V_OFF;
        float* bijT  = ws + BIJ_OFF;
        unsigned* bar = (unsigned*)(ws + FL_TOTAL);

        hipMemsetAsync(bar, 0, 2 * sizeof(unsigned), stream);
        k_fused<<<NBLK_, 256, 0, stream>>>(x, Wm, xT, spart, v, bijT, bar, out);
        return;
    }

    const size_t t2_need = (XT_N + SP_N + V_N + BIJ_N) * sizeof(float);

    if (ws_size >= t2_need) {
        // ---------------- tier 2: round-6 pipeline ----------------
        float* xT    = ws + XT_OFF;
        float* spart = ws + SP_OFF;
        float* v     = ws + V_OFF;
        float* bijT  = ws + BIJ_OFF;

        k_tr<<<1152, 256, 0, stream>>>(x, xT);
        hipMemsetAsync(bijT, 0, C_ * R_ * sizeof(float), stream);

        const dim3 gs(C_, KS2_);

        k_s4<true><<<gs, 256, 0, stream>>>(xT, Wm, bijT, spart);
        k_v3<false><<<NBLK_, 256, 0, stream>>>(spart, v);
        k_a4<<<R_ / RT_, 640, 0, stream>>>(xT, Wm, v, bijT);

        k_s4<false><<<gs, 256, 0, stream>>>(xT, Wm, bijT, spart);
        k_v3<false><<<NBLK_, 256, 0, stream>>>(spart, v);
        k_a4<<<R_ / RT_, 640, 0, stream>>>(xT, Wm, v, bijT);

        k_s4<false><<<gs, 256, 0, stream>>>(xT, Wm, bijT, spart);
        k_v3<true><<<NBLK_, 256, 0, stream>>>(spart, out);
    } else {
        // ---------------- tier 3 ----------------
        float* s_buf = ws;
        float* cij   = ws + 40960;
        float* bij   = cij + R_ * C_;
        float* amean = bij + R_ * C_;

        const dim3 gs(KSF_, C_, B_ / MBF_);

        hipMemsetAsync(bij, 0, R_ * C_ * sizeof(float), stream);

        hipMemsetAsync(s_buf, 0, B_ * CO_ * sizeof(float), stream);
        k_s_f<true><<<gs, 256, 0, stream>>>(x, Wm, cij, s_buf);
        k_a_f<<<R_ / 2, 256, 0, stream>>>(x, Wm, s_buf, amean);
        k_soft<<<C_, 256, 0, stream>>>(amean, bij, cij);

        hipMemsetAsync(s_buf, 0, B_ * CO_ * sizeof(float), stream);
        k_s_f<false><<<gs, 256, 0, stream>>>(x, Wm, cij, s_buf);
        k_a_f<<<R_ / 2, 256, 0, stream>>>(x, Wm, s_buf, amean);
        k_soft<<<C_, 256, 0, stream>>>(amean, bij, cij);

        hipMemsetAsync(out, 0, B_ * CO_ * sizeof(float), stream);
        k_s_f<false><<<gs, 256, 0, stream>>>(x, Wm, cij, out);
        k_squash<<<(B_ * CO_ + 255) / 256, 256, 0, stream>>>(out);
    }
}

// Round 9
// 213.860 us; speedup vs baseline: 1.3631x; 1.0333x over previous
//
#include <hip/hip_runtime.h>
#include <math.h>

namespace {

constexpr int B_ = 256;
constexpr int R_ = 1152;
constexpr int C_ = 10;
constexpr int O_ = 16;
constexpr int I_ = 8;
constexpr int CO_ = C_ * O_;          // 160
constexpr int WRI_ = C_ * O_ * I_;    // 1280 floats of W per route

constexpr int KS2_ = 64;              // r-splits in k_s5
constexpr int RC2_ = R_ / KS2_;       // 18 routes per block
constexpr int RT_  = 4;               // routes per k_a4 block
constexpr int NBLK_ = 640;

// fallback tier-3 params
constexpr int KSF_ = 16;
constexpr int RCF_ = R_ / KSF_;       // 72
constexpr int MBF_ = 16;

// ws layout (float offsets)
constexpr size_t XT_OFF    = 0;                          // [R][B][I]
constexpr size_t XT_N      = (size_t)R_ * B_ * I_;       // 2,359,296
constexpr size_t SP_OFF    = XT_OFF + XT_N;              // [CO][KS2][B]
constexpr size_t SP_N      = (size_t)CO_ * KS2_ * B_;    // 2,621,440
constexpr size_t V_OFF     = SP_OFF + SP_N;              // [B][CO]
constexpr size_t V_N       = (size_t)B_ * CO_;           // 40,960
constexpr size_t BIJ_OFF   = V_OFF + V_N;                // [C][R]
constexpr size_t BIJ_N     = (size_t)C_ * R_;            // 11,520
constexpr size_t FL_TOTAL  = BIJ_OFF + BIJ_N;

__device__ __forceinline__ float squashf(float s) {
    // faithful to reference: s^2*s/((1+s^2)*sqrt(s^2)) == s*|s|/(1+s^2)
    return s * fabsf(s) / (1.0f + s * s);
}

// ===========================================================================
// k_tr2: x[b,r,i] -> xT[r,b,i] (+ zero bijT, folding out the memset node).
// tile: 8 b x 32 r.  grid 36*32=1152, 256 thr.
// ===========================================================================
__global__ __launch_bounds__(256) void k_tr2(const float* __restrict__ x,
                                             float* __restrict__ xT,
                                             float* __restrict__ bijT) {
    __shared__ float t[8][32][8];
    const int tid = threadIdx.x;
    {
        const int gi = blockIdx.x * 256 + tid;
        if (gi < C_ * R_) bijT[gi] = 0.f;
    }
    const int r0 = (blockIdx.x % 36) * 32;
    const int b0 = (blockIdx.x / 36) * 8;
    {
        const int rl = tid & 31, bl = tid >> 5;
        const float4* p = (const float4*)(x + ((size_t)(b0 + bl) * R_ + (r0 + rl)) * I_);
        const float4 a0 = p[0], a1 = p[1];
        float* d = &t[bl][rl][0];
        *(float4*)d = a0;
        *(float4*)(d + 4) = a1;
    }
    __syncthreads();
    {
        const int f = tid & 7, rw = tid >> 3;   // f = b-local
        const float* s8 = &t[f][rw][0];
        const float4 a0 = *(const float4*)s8, a1 = *(const float4*)(s8 + 4);
        float* d = xT + ((size_t)(r0 + rw) * B_ + (b0 + f)) * I_;
        *(float4*)d = a0;
        *(float4*)(d + 4) = a1;
    }
}

// ===========================================================================
// k_s5: spart[c*O+o, ks, b] = sum_{r in chunk} softmax_r(bij[c,:]) *
//                             dot(W[r,c,o,:], xT[r,b,:])
// grid (C_, KS2_), 256 thr = 4 waves; wave owns a 4-o tile; lane owns 4 b's.
// W chunk (18 r x 128 = 9.2 KB) staged in LDS once (coalesced), read back
// with wave-uniform ds_read_b128 (broadcast, conflict-free) -> removes the
// serial s_load latency chain that throttled k_s4.
// ===========================================================================
template <bool UNIFORM>
__global__ __launch_bounds__(256) void k_s5(const float* __restrict__ xT,
                                            const float* __restrict__ Wm,
                                            const float* __restrict__ bijT,
                                            float* __restrict__ spart) {
    __shared__ __align__(16) float wlds[RC2_ * 128];   // 2304 floats = 9.2 KB
    __shared__ float cwch[RC2_];
    __shared__ float sred[8];

    const int tid  = threadIdx.x;
    const int lane = tid & 63;
    const int c    = blockIdx.x;          // 0..9
    const int ks   = blockIdx.y;          // 0..KS2_-1
    const int r0   = ks * RC2_;

    // ---- stage W chunk: rows r0..r0+17, capsule c (128 floats each) ----
    {
        const float4* src = (const float4*)(Wm + ((size_t)r0 * C_ + c) * 128);
        float4* dst = (float4*)wlds;
        #pragma unroll
        for (int k = 0; k < (RC2_ * 32 + 255) / 256; ++k) {
            const int idx = tid + 256 * k;             // 0..575
            if (idx < RC2_ * 32) {
                const int r = idx >> 5, q = idx & 31;
                dst[idx] = src[(size_t)r * (C_ * 32) + q];
            }
        }
    }

    // ---- softmax over routes for capsule c ----
    if (!UNIFORM) {
        const float* bc = bijT + (size_t)c * R_;
        float bv[5];
        #pragma unroll
        for (int k = 0; k < 5; ++k) {
            const int r = tid + 256 * k;
            bv[k] = (r < R_) ? bc[r] : -1e30f;
        }
        float m = -1e30f;
        #pragma unroll
        for (int k = 0; k < 5; ++k) m = fmaxf(m, bv[k]);
        #pragma unroll
        for (int off = 32; off > 0; off >>= 1)
            m = fmaxf(m, __shfl_down(m, off, 64));
        if (lane == 0) sred[tid >> 6] = m;
        __syncthreads();
        const float bm = fmaxf(fmaxf(sred[0], sred[1]), fmaxf(sred[2], sred[3]));
        float se = 0.f;
        #pragma unroll
        for (int k = 0; k < 5; ++k)
            se += (bv[k] > -1e29f) ? expf(bv[k] - bm) : 0.f;
        #pragma unroll
        for (int off = 32; off > 0; off >>= 1)
            se += __shfl_down(se, off, 64);
        if (lane == 0) sred[4 + (tid >> 6)] = se;
        __syncthreads();
        const float inv = 1.0f / (sred[4] + sred[5] + sred[6] + sred[7]);
        if (tid < RC2_) cwch[tid] = expf(bc[r0 + tid] - bm) * inv;
    }
    __syncthreads();

    const int o0 = (tid >> 6) * 4;        // wave-uniform; LDS reads broadcast

    float acc[4][4];                      // [oo][bb]
    #pragma unroll
    for (int oo = 0; oo < 4; ++oo)
        #pragma unroll
        for (int bb = 0; bb < 4; ++bb) acc[oo][bb] = 0.f;

    const float* xbase = xT + ((size_t)r0 * B_ + lane) * I_;

    #pragma unroll 2
    for (int r = 0; r < RC2_; ++r) {
        // x fragments: 4 b's, coalesced (lane-stride 32 B)
        float4 xa[4][2];
        #pragma unroll
        for (int bb = 0; bb < 4; ++bb) {
            const float4* xp =
                (const float4*)(xbase + (size_t)r * B_ * I_ + bb * 64 * I_);
            xa[bb][0] = xp[0];
            xa[bb][1] = xp[1];
        }
        // W fragment from LDS: wave-uniform address -> broadcast
        const float4* wl = (const float4*)&wlds[r * 128 + o0 * 8];
        float4 w[4][2];
        #pragma unroll
        for (int oo = 0; oo < 4; ++oo) {
            w[oo][0] = wl[oo * 2 + 0];
            w[oo][1] = wl[oo * 2 + 1];
        }
        const float cw = UNIFORM ? (1.0f / (float)R_) : cwch[r];
        #pragma unroll
        for (int oo = 0; oo < 4; ++oo) {
            #pragma unroll
            for (int bb = 0; bb < 4; ++bb) {
                const float p0 = fmaf(xa[bb][0].y, w[oo][0].y, xa[bb][0].x * w[oo][0].x);
                const float p1 = fmaf(xa[bb][0].w, w[oo][0].w, xa[bb][0].z * w[oo][0].z);
                const float p2 = fmaf(xa[bb][1].y, w[oo][1].y, xa[bb][1].x * w[oo][1].x);
                const float p3 = fmaf(xa[bb][1].w, w[oo][1].w, xa[bb][1].z * w[oo][1].z);
                acc[oo][bb] = fmaf(cw, (p0 + p1) + (p2 + p3), acc[oo][bb]);
            }
        }
    }

    // store: spart[c*O + o0+oo][ks][bb*64 + lane]  (lane-contiguous)
    float* sp = spart + (((size_t)(c * O_ + o0)) * KS2_ + ks) * B_ + lane;
    #pragma unroll
    for (int oo = 0; oo < 4; ++oo)
        #pragma unroll
        for (int bb = 0; bb < 4; ++bb)
            sp[(size_t)oo * KS2_ * B_ + bb * 64] = acc[oo][bb];
}

// ===========================================================================
// k_v3: vout[b,co] = squash(sum_ks spart[co,ks,b]).  grid NBLK_, 256 thr.
// ===========================================================================
__global__ __launch_bounds__(256) void k_v3(const float* __restrict__ spart,
                                            float* __restrict__ vout) {
    __shared__ float sh[192];
    const int tid  = threadIdx.x;
    const int lane = tid & 63;
    const int g    = tid >> 6;
    const int co2  = blockIdx.x % CO_;
    const int bseg = blockIdx.x / CO_;
    const float* p = spart + (((size_t)co2) * KS2_ + g * 16) * B_ + bseg * 64 + lane;
    float t0 = 0.f, t1 = 0.f, t2 = 0.f, t3 = 0.f;
    #pragma unroll
    for (int j = 0; j < 16; j += 4) {
        t0 += p[(size_t)(j + 0) * B_];
        t1 += p[(size_t)(j + 1) * B_];
        t2 += p[(size_t)(j + 2) * B_];
        t3 += p[(size_t)(j + 3) * B_];
    }
    const float s = (t0 + t1) + (t2 + t3);
    if (g) sh[(g - 1) * 64 + lane] = s;
    __syncthreads();
    if (g == 0) {
        const float tot = s + sh[lane] + sh[64 + lane] + sh[128 + lane];
        const int b = bseg * 64 + lane;
        vout[(size_t)b * CO_ + co2] = squashf(tot);
    }
}

// ===========================================================================
// k_a4: bijT[c, r0+rr] += (1/B) sum_o sum_i W[r,c,o,i]*(sum_b v[b,c,o]*xT[r,b,i])
// grid R_/RT_ blocks, 640 thr = 160 co x 4 b-groups of 64.
// ===========================================================================
__global__ __launch_bounds__(640) void k_a4(const float* __restrict__ xT,
                                            const float* __restrict__ Wm,
                                            const float* __restrict__ v,
                                            float* __restrict__ bijT) {
    __shared__ __align__(16) float xrow[RT_ * B_ * I_];
    __shared__ float part[RT_][640];

    const int tid = threadIdx.x;
    const int r0  = blockIdx.x * RT_;

    for (int k = tid; k < RT_ * B_ * I_ / 4; k += 640)
        ((float4*)xrow)[k] = ((const float4*)(xT + (size_t)r0 * B_ * I_))[k];
    __syncthreads();

    const int co = tid % CO_;
    const int bg = tid / CO_;
    const int b0 = bg * 64;

    float acc[RT_][8];
    #pragma unroll
    for (int rr = 0; rr < RT_; ++rr)
        #pragma unroll
        for (int i = 0; i < 8; ++i) acc[rr][i] = 0.f;

    const float* vp = v + co;
    #pragma unroll 2
    for (int bb = 0; bb < 64; ++bb) {
        const int b = b0 + bb;
        const float vt = vp[(size_t)b * CO_];
        #pragma unroll
        for (int rr = 0; rr < RT_; ++rr) {
            const float4 y0 = *(const float4*)(&xrow[(rr * B_ + b) * I_]);
            const float4 y1 = *(const float4*)(&xrow[(rr * B_ + b) * I_ + 4]);
            acc[rr][0] = fmaf(vt, y0.x, acc[rr][0]);
            acc[rr][1] = fmaf(vt, y0.y, acc[rr][1]);
            acc[rr][2] = fmaf(vt, y0.z, acc[rr][2]);
            acc[rr][3] = fmaf(vt, y0.w, acc[rr][3]);
            acc[rr][4] = fmaf(vt, y1.x, acc[rr][4]);
            acc[rr][5] = fmaf(vt, y1.y, acc[rr][5]);
            acc[rr][6] = fmaf(vt, y1.z, acc[rr][6]);
            acc[rr][7] = fmaf(vt, y1.w, acc[rr][7]);
        }
    }

    #pragma unroll
    for (int rr = 0; rr < RT_; ++rr) {
        const float* wp = Wm + (((size_t)(r0 + rr)) * CO_ + co) * I_;
        const float4 w0 = *(const float4*)wp;
        const float4 w1 = *(const float4*)(wp + 4);
        const float p0 = fmaf(acc[rr][1], w0.y, acc[rr][0] * w0.x);
        const float p1 = fmaf(acc[rr][3], w0.w, acc[rr][2] * w0.z);
        const float p2 = fmaf(acc[rr][5], w1.y, acc[rr][4] * w1.x);
        const float p3 = fmaf(acc[rr][7], w1.w, acc[rr][6] * w1.z);
        part[rr][tid] = (p0 + p1) + (p2 + p3);
    }
    __syncthreads();

    if (tid < CO_) {
        #pragma unroll
        for (int rr = 0; rr < RT_; ++rr) {
            float a = part[rr][tid] + part[rr][CO_ + tid] +
                      part[rr][2 * CO_ + tid] + part[rr][3 * CO_ + tid];
            #pragma unroll
            for (int off = 8; off > 0; off >>= 1)
                a += __shfl_down(a, off, 16);
            if ((tid & 15) == 0)
                bijT[(size_t)(tid >> 4) * R_ + (r0 + rr)] += a * (1.0f / (float)B_);
        }
    }
}

// ===========================================================================
// FALLBACK tier 3 (tiny ws)
// ===========================================================================
template <bool UNIFORM>
__global__ __launch_bounds__(256) void k_s_f(const float* __restrict__ x,
                                             const float* __restrict__ Wm,
                                             const float* __restrict__ cij,
                                             float* __restrict__ s_out) {
    const int o  = threadIdx.x & 15;
    const int tb = threadIdx.x >> 4;
    const int b  = blockIdx.z * MBF_ + tb;
    const int c  = blockIdx.y;
    const int r0 = blockIdx.x * RCF_;

    const float* xp = x + ((size_t)b * R_ + r0) * I_;
    const float* wp = Wm + (((size_t)r0 * C_ + c) * O_ + o) * I_;
    const float* cp = cij + (size_t)r0 * C_ + c;

    float acc = 0.f;
    #pragma unroll 4
    for (int r = 0; r < RCF_; ++r) {
        const float4 xv0 = *(const float4*)(xp);
        const float4 xv1 = *(const float4*)(xp + 4);
        const float4 wv0 = *(const float4*)(wp);
        const float4 wv1 = *(const float4*)(wp + 4);
        const float p0 = fmaf(xv0.y, wv0.y, xv0.x * wv0.x);
        const float p1 = fmaf(xv0.w, wv0.w, xv0.z * wv0.z);
        const float p2 = fmaf(xv1.y, wv1.y, xv1.x * wv1.x);
        const float p3 = fmaf(xv1.w, wv1.w, xv1.z * wv1.z);
        const float cw = UNIFORM ? (1.0f / (float)R_) : cp[0];
        acc = fmaf(cw, (p0 + p1) + (p2 + p3), acc);
        xp += I_;
        wp += WRI_;
        cp += C_;
    }
    atomicAdd(&s_out[((size_t)b * C_ + c) * O_ + o], acc);
}

__global__ __launch_bounds__(256) void k_a_f(const float* __restrict__ x,
                                             const float* __restrict__ Wm,
                                             const float* __restrict__ s_in,
                                             float* __restrict__ amean) {
    __shared__ __align__(16) float wlds[2 * WRI_];
    __shared__ float red[4][2 * C_];

    const int tid = threadIdx.x;
    const int r0  = blockIdx.x * 2;

    const float* wsrc = Wm + (size_t)r0 * WRI_;
    #pragma unroll
    for (int k = 0; k < 2 * WRI_ / 256; ++k)
        wlds[tid + 256 * k] = wsrc[tid + 256 * k];
    __syncthreads();

    const int b    = tid;
    const int lane = tid & 63;
    const int wv   = tid >> 6;

    float xv[2][I_];
    const float4* xp4 = (const float4*)(x + ((size_t)b * R_ + r0) * I_);
    #pragma unroll
    for (int rr = 0; rr < 2; ++rr) {
        const float4 a0 = xp4[rr * 2 + 0];
        const float4 a1 = xp4[rr * 2 + 1];
        xv[rr][0] = a0.x; xv[rr][1] = a0.y; xv[rr][2] = a0.z; xv[rr][3] = a0.w;
        xv[rr][4] = a1.x; xv[rr][5] = a1.y; xv[rr][6] = a1.z; xv[rr][7] = a1.w;
    }

    #pragma unroll 1
    for (int c = 0; c < C_; ++c) {
        const float4* sp4 = (const float4*)(s_in + ((size_t)b * C_ + c) * O_);
        float v[O_];
        #pragma unroll
        for (int q = 0; q < 4; ++q) {
            const float4 sv = sp4[q];
            v[q * 4 + 0] = squashf(sv.x);
            v[q * 4 + 1] = squashf(sv.y);
            v[q * 4 + 2] = squashf(sv.z);
            v[q * 4 + 3] = squashf(sv.w);
        }
        #pragma unroll 1
        for (int rr = 0; rr < 2; ++rr) {
            const float4* wl4 = (const float4*)&wlds[(rr * C_ + c) * O_ * I_];
            float a = 0.f;
            #pragma unroll
            for (int o = 0; o < O_; ++o) {
                const float4 w0 = wl4[o * 2 + 0];
                const float4 w1 = wl4[o * 2 + 1];
                float u = xv[rr][0] * w0.x;
                u = fmaf(xv[rr][1], w0.y, u);
                u = fmaf(xv[rr][2], w0.z, u);
                u = fmaf(xv[rr][3], w0.w, u);
                u = fmaf(xv[rr][4], w1.x, u);
                u = fmaf(xv[rr][5], w1.y, u);
                u = fmaf(xv[rr][6], w1.z, u);
                u = fmaf(xv[rr][7], w1.w, u);
                a = fmaf(u, v[o], a);
            }
            #pragma unroll
            for (int off = 32; off > 0; off >>= 1)
                a += __shfl_down(a, off, 64);
            if (lane == 0) red[wv][rr * C_ + c] = a;
        }
    }

    __syncthreads();
    if (tid < 2 * C_) {
        const float t = red[0][tid] + red[1][tid] + red[2][tid] + red[3][tid];
        const int rr = tid / C_;
        const int c  = tid % C_;
        amean[(size_t)(r0 + rr) * C_ + c] = t * (1.0f / (float)B_);
    }
}

__global__ __launch_bounds__(256) void k_soft(const float* __restrict__ amean,
                                              float* __restrict__ bij,
                                              float* __restrict__ cij) {
    const int c   = blockIdx.x;
    const int tid = threadIdx.x;
    __shared__ float sred[4];

    float vals[5];
    float m = -1e30f;
    #pragma unroll
    for (int k = 0; k < 5; ++k) {
        const int r = tid + 256 * k;
        if (r < R_) {
            const size_t idx = (size_t)r * C_ + c;
            const float vv = bij[idx] + amean[idx];
            bij[idx] = vv;
            vals[k] = vv;
            m = fmaxf(m, vv);
        } else {
            vals[k] = -1e30f;
        }
    }
    #pragma unroll
    for (int off = 32; off > 0; off >>= 1)
        m = fmaxf(m, __shfl_down(m, off, 64));
    if ((tid & 63) == 0) sred[tid >> 6] = m;
    __syncthreads();
    const float bm = fmaxf(fmaxf(sred[0], sred[1]), fmaxf(sred[2], sred[3]));
    __syncthreads();

    float se = 0.f;
    #pragma unroll
    for (int k = 0; k < 5; ++k)
        se += (vals[k] > -1e29f) ? expf(vals[k] - bm) : 0.f;
    #pragma unroll
    for (int off = 32; off > 0; off >>= 1)
        se += __shfl_down(se, off, 64);
    if ((tid & 63) == 0) sred[tid >> 6] = se;
    __syncthreads();
    const float inv = 1.0f / (sred[0] + sred[1] + sred[2] + sred[3]);

    #pragma unroll
    for (int k = 0; k < 5; ++k) {
        const int r = tid + 256 * k;
        if (r < R_) cij[(size_t)r * C_ + c] = expf(vals[k] - bm) * inv;
    }
}

__global__ __launch_bounds__(256) void k_squash(float* __restrict__ s) {
    const int idx = blockIdx.x * 256 + threadIdx.x;
    if (idx < B_ * CO_) s[idx] = squashf(s[idx]);
}

} // namespace

extern "C" void kernel_launch(void* const* d_in, const int* in_sizes, int n_in,
                              void* d_out, int out_size, void* d_ws, size_t ws_size,
                              hipStream_t stream) {
    const float* x  = (const float*)d_in[0];   // [256,1152,8]
    const float* Wm = (const float*)d_in[1];   // [1152,10,16,8]
    float* out = (float*)d_out;                // [256,10,16] flat = 40960
    float* ws  = (float*)d_ws;

    const size_t need = FL_TOTAL * sizeof(float);

    if (ws_size >= need) {
        // ---------------- main path: 9 nodes ----------------
        float* xT    = ws + XT_OFF;
        float* spart = ws + SP_OFF;
        float* v     = ws + V_OFF;
        float* bijT  = ws + BIJ_OFF;

        const dim3 gs(C_, KS2_);                  // 640 blocks

        k_tr2<<<1152, 256, 0, stream>>>(x, xT, bijT);

        // iter 0 (uniform weights; softmax(0) == 1/R)
        k_s5<true><<<gs, 256, 0, stream>>>(xT, Wm, bijT, spart);
        k_v3<<<NBLK_, 256, 0, stream>>>(spart, v);
        k_a4<<<R_ / RT_, 640, 0, stream>>>(xT, Wm, v, bijT);

        // iter 1
        k_s5<false><<<gs, 256, 0, stream>>>(xT, Wm, bijT, spart);
        k_v3<<<NBLK_, 256, 0, stream>>>(spart, v);
        k_a4<<<R_ / RT_, 640, 0, stream>>>(xT, Wm, v, bijT);

        // iter 2: final v straight into d_out
        k_s5<false><<<gs, 256, 0, stream>>>(xT, Wm, bijT, spart);
        k_v3<<<NBLK_, 256, 0, stream>>>(spart, out);
    } else {
        // ---------------- tier 3 ----------------
        float* s_buf = ws;
        float* cij   = ws + 40960;
        float* bij   = cij + R_ * C_;
        float* amean = bij + R_ * C_;

        const dim3 gsf(KSF_, C_, B_ / MBF_);

        hipMemsetAsync(bij, 0, R_ * C_ * sizeof(float), stream);

        hipMemsetAsync(s_buf, 0, B_ * CO_ * sizeof(float), stream);
        k_s_f<true><<<gsf, 256, 0, stream>>>(x, Wm, cij, s_buf);
        k_a_f<<<R_ / 2, 256, 0, stream>>>(x, Wm, s_buf, amean);
        k_soft<<<C_, 256, 0, stream>>>(amean, bij, cij);

        hipMemsetAsync(s_buf, 0, B_ * CO_ * sizeof(float), stream);
        k_s_f<false><<<gsf, 256, 0, stream>>>(x, Wm, cij, s_buf);
        k_a_f<<<R_ / 2, 256, 0, stream>>>(x, Wm, s_buf, amean);
        k_soft<<<C_, 256, 0, stream>>>(amean, bij, cij);

        hipMemsetAsync(out, 0, B_ * CO_ * sizeof(float), stream);
        k_s_f<false><<<gsf, 256, 0, stream>>>(x, Wm, cij, out);
        k_squash<<<(B_ * CO_ + 255) / 256, 256, 0, stream>>>(out);
    }
}

// Round 10
// 209.334 us; speedup vs baseline: 1.3926x; 1.0216x over previous
//
#include <hip/hip_runtime.h>
#include <math.h>

namespace {

constexpr int B_ = 256;
constexpr int R_ = 1152;
constexpr int C_ = 10;
constexpr int O_ = 16;
constexpr int I_ = 8;
constexpr int CO_ = C_ * O_;          // 160
constexpr int WRI_ = C_ * O_ * I_;    // 1280 floats of W per route

constexpr int KS2_ = 64;              // r-splits in k_s5
constexpr int RC2_ = R_ / KS2_;       // 18 routes per block
constexpr int RT_  = 4;               // routes per k_a4 block
constexpr int NBLK_ = 640;

// fallback tier-3 params
constexpr int KSF_ = 16;
constexpr int RCF_ = R_ / KSF_;       // 72
constexpr int MBF_ = 16;

// ws layout (float offsets)
constexpr size_t XT_OFF    = 0;                          // [R][B][I]
constexpr size_t XT_N      = (size_t)R_ * B_ * I_;       // 2,359,296
constexpr size_t SP_OFF    = XT_OFF + XT_N;              // [CO][KS2][B]
constexpr size_t SP_N      = (size_t)CO_ * KS2_ * B_;    // 2,621,440
constexpr size_t V_OFF     = SP_OFF + SP_N;              // [B][CO]
constexpr size_t V_N       = (size_t)B_ * CO_;           // 40,960
constexpr size_t BIJ_OFF   = V_OFF + V_N;                // [C][R]
constexpr size_t BIJ_N     = (size_t)C_ * R_;            // 11,520
constexpr size_t FL_TOTAL  = BIJ_OFF + BIJ_N;

__device__ __forceinline__ float squashf(float s) {
    // faithful to reference: s^2*s/((1+s^2)*sqrt(s^2)) == s*|s|/(1+s^2)
    return s * fabsf(s) / (1.0f + s * s);
}

// ===========================================================================
// k_tr2: x[b,r,i] -> xT[r,b,i] (+ zero bijT).  tile 8 b x 32 r.  grid 1152.
// ===========================================================================
__global__ __launch_bounds__(256) void k_tr2(const float* __restrict__ x,
                                             float* __restrict__ xT,
                                             float* __restrict__ bijT) {
    __shared__ float t[8][32][8];
    const int tid = threadIdx.x;
    {
        const int gi = blockIdx.x * 256 + tid;
        if (gi < C_ * R_) bijT[gi] = 0.f;
    }
    const int r0 = (blockIdx.x % 36) * 32;
    const int b0 = (blockIdx.x / 36) * 8;
    {
        const int rl = tid & 31, bl = tid >> 5;
        const float4* p = (const float4*)(x + ((size_t)(b0 + bl) * R_ + (r0 + rl)) * I_);
        const float4 a0 = p[0], a1 = p[1];
        float* d = &t[bl][rl][0];
        *(float4*)d = a0;
        *(float4*)(d + 4) = a1;
    }
    __syncthreads();
    {
        const int f = tid & 7, rw = tid >> 3;   // f = b-local
        const float* s8 = &t[f][rw][0];
        const float4 a0 = *(const float4*)s8, a1 = *(const float4*)(s8 + 4);
        float* d = xT + ((size_t)(r0 + rw) * B_ + (b0 + f)) * I_;
        *(float4*)d = a0;
        *(float4*)(d + 4) = a1;
    }
}

// ===========================================================================
// k_s5: spart[c*O+o, ks, b] = sum_{r in chunk} softmax_r(bij[c,:]) *
//                             dot(W[r,c,o,:], xT[r,b,:])
// grid (C_, KS2_), 256 thr = 4 waves; wave owns 4-o tile; lane owns 4 b's.
// W chunk staged in LDS (broadcast b128 reads).  Inner loop in outer-product
// form: cw folded into x fragment (32 ops) + 128 pure fma -> 160 VALU ops/r
// vs 192 for the reduction-tree form (-17% VALU).
// ===========================================================================
template <bool UNIFORM>
__global__ __launch_bounds__(256) void k_s5(const float* __restrict__ xT,
                                            const float* __restrict__ Wm,
                                            const float* __restrict__ bijT,
                                            float* __restrict__ spart) {
    __shared__ __align__(16) float wlds[RC2_ * 128];   // 2304 floats = 9.2 KB
    __shared__ float cwch[RC2_];
    __shared__ float sred[8];

    const int tid  = threadIdx.x;
    const int lane = tid & 63;
    const int c    = blockIdx.x;          // 0..9
    const int ks   = blockIdx.y;          // 0..KS2_-1
    const int r0   = ks * RC2_;

    // ---- stage W chunk: rows r0..r0+17, capsule c (128 floats each) ----
    {
        const float4* src = (const float4*)(Wm + ((size_t)r0 * C_ + c) * 128);
        float4* dst = (float4*)wlds;
        #pragma unroll
        for (int k = 0; k < (RC2_ * 32 + 255) / 256; ++k) {
            const int idx = tid + 256 * k;             // 0..575
            if (idx < RC2_ * 32) {
                const int r = idx >> 5, q = idx & 31;
                dst[idx] = src[(size_t)r * (C_ * 32) + q];
            }
        }
    }

    // ---- softmax over routes for capsule c ----
    if (!UNIFORM) {
        const float* bc = bijT + (size_t)c * R_;
        float bv[5];
        #pragma unroll
        for (int k = 0; k < 5; ++k) {
            const int r = tid + 256 * k;
            bv[k] = (r < R_) ? bc[r] : -1e30f;
        }
        float m = -1e30f;
        #pragma unroll
        for (int k = 0; k < 5; ++k) m = fmaxf(m, bv[k]);
        #pragma unroll
        for (int off = 32; off > 0; off >>= 1)
            m = fmaxf(m, __shfl_down(m, off, 64));
        if (lane == 0) sred[tid >> 6] = m;
        __syncthreads();
        const float bm = fmaxf(fmaxf(sred[0], sred[1]), fmaxf(sred[2], sred[3]));
        float se = 0.f;
        #pragma unroll
        for (int k = 0; k < 5; ++k)
            se += (bv[k] > -1e29f) ? expf(bv[k] - bm) : 0.f;
        #pragma unroll
        for (int off = 32; off > 0; off >>= 1)
            se += __shfl_down(se, off, 64);
        if (lane == 0) sred[4 + (tid >> 6)] = se;
        __syncthreads();
        const float inv = 1.0f / (sred[4] + sred[5] + sred[6] + sred[7]);
        if (tid < RC2_) cwch[tid] = expf(bc[r0 + tid] - bm) * inv;
    }
    __syncthreads();

    const int o0 = (tid >> 6) * 4;        // wave-uniform; LDS reads broadcast

    float acc[4][4];                      // [oo][bb]
    #pragma unroll
    for (int oo = 0; oo < 4; ++oo)
        #pragma unroll
        for (int bb = 0; bb < 4; ++bb) acc[oo][bb] = 0.f;

    const float* xbase = xT + ((size_t)r0 * B_ + lane) * I_;

    #pragma unroll 2
    for (int r = 0; r < RC2_; ++r) {
        const float cw = UNIFORM ? (1.0f / (float)R_) : cwch[r];
        // x fragments: 4 b's, coalesced; cw folded in (outer-product form)
        float xs[4][8];
        #pragma unroll
        for (int bb = 0; bb < 4; ++bb) {
            const float4* xp =
                (const float4*)(xbase + (size_t)r * B_ * I_ + bb * 64 * I_);
            const float4 a0 = xp[0], a1 = xp[1];
            xs[bb][0] = a0.x * cw; xs[bb][1] = a0.y * cw;
            xs[bb][2] = a0.z * cw; xs[bb][3] = a0.w * cw;
            xs[bb][4] = a1.x * cw; xs[bb][5] = a1.y * cw;
            xs[bb][6] = a1.z * cw; xs[bb][7] = a1.w * cw;
        }
        // W fragment from LDS: wave-uniform address -> broadcast
        const float4* wl = (const float4*)&wlds[r * 128 + o0 * 8];
        #pragma unroll
        for (int oo = 0; oo < 4; ++oo) {
            const float4 w0 = wl[oo * 2 + 0];
            const float4 w1 = wl[oo * 2 + 1];
            #pragma unroll
            for (int bb = 0; bb < 4; ++bb) {
                float a = acc[oo][bb];
                a = fmaf(xs[bb][0], w0.x, a);
                a = fmaf(xs[bb][1], w0.y, a);
                a = fmaf(xs[bb][2], w0.z, a);
                a = fmaf(xs[bb][3], w0.w, a);
                a = fmaf(xs[bb][4], w1.x, a);
                a = fmaf(xs[bb][5], w1.y, a);
                a = fmaf(xs[bb][6], w1.z, a);
                a = fmaf(xs[bb][7], w1.w, a);
                acc[oo][bb] = a;
            }
        }
    }

    // store: spart[c*O + o0+oo][ks][bb*64 + lane]  (lane-contiguous)
    float* sp = spart + (((size_t)(c * O_ + o0)) * KS2_ + ks) * B_ + lane;
    #pragma unroll
    for (int oo = 0; oo < 4; ++oo)
        #pragma unroll
        for (int bb = 0; bb < 4; ++bb)
            sp[(size_t)oo * KS2_ * B_ + bb * 64] = acc[oo][bb];
}

// ===========================================================================
// k_v3: vout[b,co] = squash(sum_ks spart[co,ks,b]).  grid NBLK_, 256 thr.
// ===========================================================================
__global__ __launch_bounds__(256) void k_v3(const float* __restrict__ spart,
                                            float* __restrict__ vout) {
    __shared__ float sh[192];
    const int tid  = threadIdx.x;
    const int lane = tid & 63;
    const int g    = tid >> 6;
    const int co2  = blockIdx.x % CO_;
    const int bseg = blockIdx.x / CO_;
    const float* p = spart + (((size_t)co2) * KS2_ + g * 16) * B_ + bseg * 64 + lane;
    float t0 = 0.f, t1 = 0.f, t2 = 0.f, t3 = 0.f;
    #pragma unroll
    for (int j = 0; j < 16; j += 4) {
        t0 += p[(size_t)(j + 0) * B_];
        t1 += p[(size_t)(j + 1) * B_];
        t2 += p[(size_t)(j + 2) * B_];
        t3 += p[(size_t)(j + 3) * B_];
    }
    const float s = (t0 + t1) + (t2 + t3);
    if (g) sh[(g - 1) * 64 + lane] = s;
    __syncthreads();
    if (g == 0) {
        const float tot = s + sh[lane] + sh[64 + lane] + sh[128 + lane];
        const int b = bseg * 64 + lane;
        vout[(size_t)b * CO_ + co2] = squashf(tot);
    }
}

// ===========================================================================
// k_a4: bijT[c, r0+rr] += (1/B) sum_o sum_i W[r,c,o,i]*(sum_b v[b,c,o]*xT[r,b,i])
// grid R_/RT_ blocks, 640 thr = 160 co x 4 b-groups of 64.
// ===========================================================================
__global__ __launch_bounds__(640) void k_a4(const float* __restrict__ xT,
                                            const float* __restrict__ Wm,
                                            const float* __restrict__ v,
                                            float* __restrict__ bijT) {
    __shared__ __align__(16) float xrow[RT_ * B_ * I_];
    __shared__ float part[RT_][640];

    const int tid = threadIdx.x;
    const int r0  = blockIdx.x * RT_;

    for (int k = tid; k < RT_ * B_ * I_ / 4; k += 640)
        ((float4*)xrow)[k] = ((const float4*)(xT + (size_t)r0 * B_ * I_))[k];
    __syncthreads();

    const int co = tid % CO_;
    const int bg = tid / CO_;
    const int b0 = bg * 64;

    float acc[RT_][8];
    #pragma unroll
    for (int rr = 0; rr < RT_; ++rr)
        #pragma unroll
        for (int i = 0; i < 8; ++i) acc[rr][i] = 0.f;

    const float* vp = v + co;
    #pragma unroll 2
    for (int bb = 0; bb < 64; ++bb) {
        const int b = b0 + bb;
        const float vt = vp[(size_t)b * CO_];
        #pragma unroll
        for (int rr = 0; rr < RT_; ++rr) {
            const float4 y0 = *(const float4*)(&xrow[(rr * B_ + b) * I_]);
            const float4 y1 = *(const float4*)(&xrow[(rr * B_ + b) * I_ + 4]);
            acc[rr][0] = fmaf(vt, y0.x, acc[rr][0]);
            acc[rr][1] = fmaf(vt, y0.y, acc[rr][1]);
            acc[rr][2] = fmaf(vt, y0.z, acc[rr][2]);
            acc[rr][3] = fmaf(vt, y0.w, acc[rr][3]);
            acc[rr][4] = fmaf(vt, y1.x, acc[rr][4]);
            acc[rr][5] = fmaf(vt, y1.y, acc[rr][5]);
            acc[rr][6] = fmaf(vt, y1.z, acc[rr][6]);
            acc[rr][7] = fmaf(vt, y1.w, acc[rr][7]);
        }
    }

    #pragma unroll
    for (int rr = 0; rr < RT_; ++rr) {
        const float* wp = Wm + (((size_t)(r0 + rr)) * CO_ + co) * I_;
        const float4 w0 = *(const float4*)wp;
        const float4 w1 = *(const float4*)(wp + 4);
        const float p0 = fmaf(acc[rr][1], w0.y, acc[rr][0] * w0.x);
        const float p1 = fmaf(acc[rr][3], w0.w, acc[rr][2] * w0.z);
        const float p2 = fmaf(acc[rr][5], w1.y, acc[rr][4] * w1.x);
        const float p3 = fmaf(acc[rr][7], w1.w, acc[rr][6] * w1.z);
        part[rr][tid] = (p0 + p1) + (p2 + p3);
    }
    __syncthreads();

    if (tid < CO_) {
        #pragma unroll
        for (int rr = 0; rr < RT_; ++rr) {
            float a = part[rr][tid] + part[rr][CO_ + tid] +
                      part[rr][2 * CO_ + tid] + part[rr][3 * CO_ + tid];
            #pragma unroll
            for (int off = 8; off > 0; off >>= 1)
                a += __shfl_down(a, off, 16);
            if ((tid & 15) == 0)
                bijT[(size_t)(tid >> 4) * R_ + (r0 + rr)] += a * (1.0f / (float)B_);
        }
    }
}

// ===========================================================================
// FALLBACK tier 3 (tiny ws)
// ===========================================================================
template <bool UNIFORM>
__global__ __launch_bounds__(256) void k_s_f(const float* __restrict__ x,
                                             const float* __restrict__ Wm,
                                             const float* __restrict__ cij,
                                             float* __restrict__ s_out) {
    const int o  = threadIdx.x & 15;
    const int tb = threadIdx.x >> 4;
    const int b  = blockIdx.z * MBF_ + tb;
    const int c  = blockIdx.y;
    const int r0 = blockIdx.x * RCF_;

    const float* xp = x + ((size_t)b * R_ + r0) * I_;
    const float* wp = Wm + (((size_t)r0 * C_ + c) * O_ + o) * I_;
    const float* cp = cij + (size_t)r0 * C_ + c;

    float acc = 0.f;
    #pragma unroll 4
    for (int r = 0; r < RCF_; ++r) {
        const float4 xv0 = *(const float4*)(xp);
        const float4 xv1 = *(const float4*)(xp + 4);
        const float4 wv0 = *(const float4*)(wp);
        const float4 wv1 = *(const float4*)(wp + 4);
        const float p0 = fmaf(xv0.y, wv0.y, xv0.x * wv0.x);
        const float p1 = fmaf(xv0.w, wv0.w, xv0.z * wv0.z);
        const float p2 = fmaf(xv1.y, wv1.y, xv1.x * wv1.x);
        const float p3 = fmaf(xv1.w, wv1.w, xv1.z * wv1.z);
        const float cw = UNIFORM ? (1.0f / (float)R_) : cp[0];
        acc = fmaf(cw, (p0 + p1) + (p2 + p3), acc);
        xp += I_;
        wp += WRI_;
        cp += C_;
    }
    atomicAdd(&s_out[((size_t)b * C_ + c) * O_ + o], acc);
}

__global__ __launch_bounds__(256) void k_a_f(const float* __restrict__ x,
                                             const float* __restrict__ Wm,
                                             const float* __restrict__ s_in,
                                             float* __restrict__ amean) {
    __shared__ __align__(16) float wlds[2 * WRI_];
    __shared__ float red[4][2 * C_];

    const int tid = threadIdx.x;
    const int r0  = blockIdx.x * 2;

    const float* wsrc = Wm + (size_t)r0 * WRI_;
    #pragma unroll
    for (int k = 0; k < 2 * WRI_ / 256; ++k)
        wlds[tid + 256 * k] = wsrc[tid + 256 * k];
    __syncthreads();

    const int b    = tid;
    const int lane = tid & 63;
    const int wv   = tid >> 6;

    float xv[2][I_];
    const float4* xp4 = (const float4*)(x + ((size_t)b * R_ + r0) * I_);
    #pragma unroll
    for (int rr = 0; rr < 2; ++rr) {
        const float4 a0 = xp4[rr * 2 + 0];
        const float4 a1 = xp4[rr * 2 + 1];
        xv[rr][0] = a0.x; xv[rr][1] = a0.y; xv[rr][2] = a0.z; xv[rr][3] = a0.w;
        xv[rr][4] = a1.x; xv[rr][5] = a1.y; xv[rr][6] = a1.z; xv[rr][7] = a1.w;
    }

    #pragma unroll 1
    for (int c = 0; c < C_; ++c) {
        const float4* sp4 = (const float4*)(s_in + ((size_t)b * C_ + c) * O_);
        float v[O_];
        #pragma unroll
        for (int q = 0; q < 4; ++q) {
            const float4 sv = sp4[q];
            v[q * 4 + 0] = squashf(sv.x);
            v[q * 4 + 1] = squashf(sv.y);
            v[q * 4 + 2] = squashf(sv.z);
            v[q * 4 + 3] = squashf(sv.w);
        }
        #pragma unroll 1
        for (int rr = 0; rr < 2; ++rr) {
            const float4* wl4 = (const float4*)&wlds[(rr * C_ + c) * O_ * I_];
            float a = 0.f;
            #pragma unroll
            for (int o = 0; o < O_; ++o) {
                const float4 w0 = wl4[o * 2 + 0];
                const float4 w1 = wl4[o * 2 + 1];
                float u = xv[rr][0] * w0.x;
                u = fmaf(xv[rr][1], w0.y, u);
                u = fmaf(xv[rr][2], w0.z, u);
                u = fmaf(xv[rr][3], w0.w, u);
                u = fmaf(xv[rr][4], w1.x, u);
                u = fmaf(xv[rr][5], w1.y, u);
                u = fmaf(xv[rr][6], w1.z, u);
                u = fmaf(xv[rr][7], w1.w, u);
                a = fmaf(u, v[o], a);
            }
            #pragma unroll
            for (int off = 32; off > 0; off >>= 1)
                a += __shfl_down(a, off, 64);
            if (lane == 0) red[wv][rr * C_ + c] = a;
        }
    }

    __syncthreads();
    if (tid < 2 * C_) {
        const float t = red[0][tid] + red[1][tid] + red[2][tid] + red[3][tid];
        const int rr = tid / C_;
        const int c  = tid % C_;
        amean[(size_t)(r0 + rr) * C_ + c] = t * (1.0f / (float)B_);
    }
}

__global__ __launch_bounds__(256) void k_soft(const float* __restrict__ amean,
                                              float* __restrict__ bij,
                                              float* __restrict__ cij) {
    const int c   = blockIdx.x;
    const int tid = threadIdx.x;
    __shared__ float sred[4];

    float vals[5];
    float m = -1e30f;
    #pragma unroll
    for (int k = 0; k < 5; ++k) {
        const int r = tid + 256 * k;
        if (r < R_) {
            const size_t idx = (size_t)r * C_ + c;
            const float vv = bij[idx] + amean[idx];
            bij[idx] = vv;
            vals[k] = vv;
            m = fmaxf(m, vv);
        } else {
            vals[k] = -1e30f;
        }
    }
    #pragma unroll
    for (int off = 32; off > 0; off >>= 1)
        m = fmaxf(m, __shfl_down(m, off, 64));
    if ((tid & 63) == 0) sred[tid >> 6] = m;
    __syncthreads();
    const float bm = fmaxf(fmaxf(sred[0], sred[1]), fmaxf(sred[2], sred[3]));
    __syncthreads();

    float se = 0.f;
    #pragma unroll
    for (int k = 0; k < 5; ++k)
        se += (vals[k] > -1e29f) ? expf(vals[k] - bm) : 0.f;
    #pragma unroll
    for (int off = 32; off > 0; off >>= 1)
        se += __shfl_down(se, off, 64);
    if ((tid & 63) == 0) sred[tid >> 6] = se;
    __syncthreads();
    const float inv = 1.0f / (sred[0] + sred[1] + sred[2] + sred[3]);

    #pragma unroll
    for (int k = 0; k < 5; ++k) {
        const int r = tid + 256 * k;
        if (r < R_) cij[(size_t)r * C_ + c] = expf(vals[k] - bm) * inv;
    }
}

__global__ __launch_bounds__(256) void k_squash(float* __restrict__ s) {
    const int idx = blockIdx.x * 256 + threadIdx.x;
    if (idx < B_ * CO_) s[idx] = squashf(s[idx]);
}

} // namespace

extern "C" void kernel_launch(void* const* d_in, const int* in_sizes, int n_in,
                              void* d_out, int out_size, void* d_ws, size_t ws_size,
                              hipStream_t stream) {
    const float* x  = (const float*)d_in[0];   // [256,1152,8]
    const float* Wm = (const float*)d_in[1];   // [1152,10,16,8]
    float* out = (float*)d_out;                // [256,10,16] flat = 40960
    float* ws  = (float*)d_ws;

    const size_t need = FL_TOTAL * sizeof(float);

    if (ws_size >= need) {
        // ---------------- main path: 9 nodes ----------------
        float* xT    = ws + XT_OFF;
        float* spart = ws + SP_OFF;
        float* v     = ws + V_OFF;
        float* bijT  = ws + BIJ_OFF;

        const dim3 gs(C_, KS2_);                  // 640 blocks

        k_tr2<<<1152, 256, 0, stream>>>(x, xT, bijT);

        // iter 0 (uniform weights; softmax(0) == 1/R)
        k_s5<true><<<gs, 256, 0, stream>>>(xT, Wm, bijT, spart);
        k_v3<<<NBLK_, 256, 0, stream>>>(spart, v);
        k_a4<<<R_ / RT_, 640, 0, stream>>>(xT, Wm, v, bijT);

        // iter 1
        k_s5<false><<<gs, 256, 0, stream>>>(xT, Wm, bijT, spart);
        k_v3<<<NBLK_, 256, 0, stream>>>(spart, v);
        k_a4<<<R_ / RT_, 640, 0, stream>>>(xT, Wm, v, bijT);

        // iter 2: final v straight into d_out
        k_s5<false><<<gs, 256, 0, stream>>>(xT, Wm, bijT, spart);
        k_v3<<<NBLK_, 256, 0, stream>>>(spart, out);
    } else {
        // ---------------- tier 3 ----------------
        float* s_buf = ws;
        float* cij   = ws + 40960;
        float* bij   = cij + R_ * C_;
        float* amean = bij + R_ * C_;

        const dim3 gsf(KSF_, C_, B_ / MBF_);

        hipMemsetAsync(bij, 0, R_ * C_ * sizeof(float), stream);

        hipMemsetAsync(s_buf, 0, B_ * CO_ * sizeof(float), stream);
        k_s_f<true><<<gsf, 256, 0, stream>>>(x, Wm, cij, s_buf);
        k_a_f<<<R_ / 2, 256, 0, stream>>>(x, Wm, s_buf, amean);
        k_soft<<<C_, 256, 0, stream>>>(amean, bij, cij);

        hipMemsetAsync(s_buf, 0, B_ * CO_ * sizeof(float), stream);
        k_s_f<false><<<gsf, 256, 0, stream>>>(x, Wm, cij, s_buf);
        k_a_f<<<R_ / 2, 256, 0, stream>>>(x, Wm, s_buf, amean);
        k_soft<<<C_, 256, 0, stream>>>(amean, bij, cij);

        hipMemsetAsync(out, 0, B_ * CO_ * sizeof(float), stream);
        k_s_f<false><<<gsf, 256, 0, stream>>>(x, Wm, cij, out);
        k_squash<<<(B_ * CO_ + 255) / 256, 256, 0, stream>>>(out);
    }
}